// Round 7
// baseline (219.128 us; speedup 1.0000x reference)
//
#include <hip/hip_runtime.h>
#include <hip/hip_bf16.h>
#include <math.h>

typedef __hip_bfloat16 bf16;
typedef __attribute__((ext_vector_type(8))) short s16x8;   // 8 bf16 (4 VGPRs)
typedef __attribute__((ext_vector_type(4))) float f32x4;

__device__ __forceinline__ float fsig(float x) {
  return __builtin_amdgcn_rcpf(1.0f + __expf(-x));
}
__device__ __forceinline__ float ftanh(float x) { return 2.0f * fsig(2.0f * x) - 1.0f; }
__device__ __forceinline__ float dot4(float4 a, float4 b) {
  return a.x * b.x + a.y * b.y + a.z * b.z + a.w * b.w;
}
__device__ __forceinline__ float wred(float s) {
#pragma unroll
  for (int off = 32; off > 0; off >>= 1) s += __shfl_down(s, off, 64);
  return s;
}
__device__ __forceinline__ float b2f(unsigned short u) {
  return __uint_as_float((unsigned)u << 16);
}
__device__ __forceinline__ float4 b2f4(ushort4 u) {
  return make_float4(b2f(u.x), b2f(u.y), b2f(u.z), b2f(u.w));
}

// Wg7 row layout (bf16, 5120 per row): [Wri 0 | Wmig 512 | Wrig 1536 | Wmrg 2048 |
//                                       Wrrg 3072 | Wmwg 3584 | Wrwg 4608]
#define WG7_STRIDE 5120

// ================= setup mega-kernel =================
// [0,12288):     cast Wcat ([Winp|Wig|Wrg]), WhoB + Wcat2-left, WencB
// [12288,14336): transpose input [512][4096] f32 -> Xb [4096][512] bf16
// [14336,15360): Wdt[k][j] = bf16(W_dec[j][k])
// [15360,16896): vout[o] = Who[o,:].b_dec (o<512) ; Web[o-512] = Wenc[o-512,:].b_dec
// [16896,18432): step-0 update inline: hidv closed-form from biases (mem0=0, no mem read)
// [18432,23552): cast 7 gate-weight matrices into row-packed bf16 Wg7[1024][5120]
__global__ void setup(const float* __restrict__ W_inp, const float* __restrict__ W_ig,
                      const float* __restrict__ W_rg, const float* __restrict__ W_ho,
                      const float* __restrict__ W_dec, const float* __restrict__ W_enc,
                      const float* __restrict__ input,
                      const float* __restrict__ Wri, const float* __restrict__ Wmig,
                      const float* __restrict__ Wrig, const float* __restrict__ Wmrg,
                      const float* __restrict__ Wrrg, const float* __restrict__ Wmwg,
                      const float* __restrict__ Wrwg,
                      const float* __restrict__ b_inp, const float* __restrict__ b_rinp,
                      const float* __restrict__ b_ig, const float* __restrict__ b_mig,
                      const float* __restrict__ b_rig, const float* __restrict__ b_wg,
                      const float* __restrict__ b_mwg, const float* __restrict__ b_rwg,
                      const float* __restrict__ b_dec, const float* __restrict__ b_enc,
                      bf16* __restrict__ Wcat,
                      bf16* __restrict__ WhoB, bf16* __restrict__ Wcat2, bf16* __restrict__ Wdt,
                      bf16* __restrict__ WencB, bf16* __restrict__ Xb,
                      float* __restrict__ out_s, float* __restrict__ mem_s,
                      float* __restrict__ vout, float* __restrict__ Web,
                      bf16* __restrict__ Wg7) {
  __shared__ float t[32][33];
  const int id = blockIdx.x, tid = threadIdx.x;
  if (id < 12288) {
    const int i = id * 256 + tid;  // < 3145728
    if (i < 524288) {
      Wcat[i] = __float2bfloat16(W_inp[i]);
    } else if (i < 1048576) {
      Wcat[i] = __float2bfloat16(W_ig[i - 524288]);
    } else if (i < 1572864) {
      Wcat[i] = __float2bfloat16(W_rg[i - 1048576]);
    } else if (i < 2097152) {
      const int k = i - 1572864;
      const bf16 vv = __float2bfloat16(W_ho[k]);
      WhoB[k] = vv;
      Wcat2[(size_t)(k >> 10) * 2048 + (k & 1023)] = vv;
    } else {
      const int k = i - 2097152;  // < 1048576
      WencB[k] = __float2bfloat16(W_enc[k]);
    }
  } else if (id < 14336) {
    const int b = id - 12288;
    const int i0 = (b >> 7) * 32, b0 = (b & 127) * 32;
    const int tx = tid & 31, ty = tid >> 5;
#pragma unroll
    for (int r = ty; r < 32; r += 8) t[r][tx] = input[(size_t)(i0 + r) * 4096 + b0 + tx];
    __syncthreads();
#pragma unroll
    for (int r = ty; r < 32; r += 8)
      Xb[(size_t)(b0 + r) * 512 + i0 + tx] = __float2bfloat16(t[tx][r]);
  } else if (id < 15360) {
    const int b = id - 14336;
    const int j0 = (b >> 5) * 32, k0 = (b & 31) * 32;
    const int tx = tid & 31, ty = tid >> 5;
#pragma unroll
    for (int r = ty; r < 32; r += 8) t[r][tx] = W_dec[(size_t)(j0 + r) * 1024 + k0 + tx];
    __syncthreads();
#pragma unroll
    for (int r = ty; r < 32; r += 8)
      Wdt[(size_t)(k0 + r) * 1024 + j0 + tx] = __float2bfloat16(t[tx][r]);
  } else if (id < 16896) {
    const int o = id - 15360;  // < 1536
    const float* row = (o < 512) ? (W_ho + (size_t)o * 1024) : (W_enc + (size_t)(o - 512) * 1024);
    const float4 a = *(const float4*)(row + tid * 4);
    const float4 b = *(const float4*)(b_dec + tid * 4);
    float s = wred(dot4(a, b));
    if ((tid & 63) == 0) t[0][tid >> 6] = s;
    __syncthreads();
    if (tid == 0) {
      const float d = t[0][0] + t[0][1] + t[0][2] + t[0][3];
      if (o < 512) vout[o] = d;
      else Web[o - 512] = d;
    }
  } else if (id < 18432) {
    const int id2 = id - 16896;  // < 1536
    const float4 bd = *(const float4*)(b_dec + tid * 4);
    const float4 v1 = *(const float4*)(b_inp + tid * 4);
    const float4 v2 = *(const float4*)(b_rinp + tid * 4);
    const float4 v3 = *(const float4*)(b_ig + tid * 4);
    const float4 v4 = *(const float4*)(b_mig + tid * 4);
    const float4 v5 = *(const float4*)(b_rig + tid * 4);
    float4 hv;
    hv.x = bd.x + fsig(v1.x + v2.x) * fsig(v3.x + v4.x + v5.x);
    hv.y = bd.y + fsig(v1.y + v2.y) * fsig(v3.y + v4.y + v5.y);
    hv.z = bd.z + fsig(v1.z + v2.z) * fsig(v3.z + v4.z + v5.z);
    hv.w = bd.w + fsig(v1.w + v2.w) * fsig(v3.w + v4.w + v5.w);
    const float* row =
        (id2 < 1024) ? (W_enc + (size_t)id2 * 1024) : (W_ho + (size_t)(id2 - 1024) * 1024);
    float s = wred(dot4(*(const float4*)(row + tid * 4), hv));
    if ((tid & 63) == 0) t[0][tid >> 6] = s;
    __syncthreads();
    if (tid == 0) {
      const float d = t[0][0] + t[0][1] + t[0][2] + t[0][3];
      if (id2 < 1024) {
        const float wg = fsig(b_wg[id2] + b_mwg[id2] + b_rwg[id2]);
        mem_s[id2] = wg * ftanh(b_enc[id2] + d);  // mem0 == 0: no mem_s read
      } else {
        out_s[id2 - 1024] = d;
      }
    }
  } else {
    // ---- Wg7 cast: block handles 1024 elems of row j, fifth f ----
    const int b = id - 18432;  // < 5120
    const int j = b / 5, f = b - j * 5;
    const int col = f * 1024 + tid * 4;
    const float* src;
    int c0, stride;
    if (col < 512)       { src = Wri;  c0 = col;        stride = 512; }
    else if (col < 1536) { src = Wmig; c0 = col - 512;  stride = 1024; }
    else if (col < 2048) { src = Wrig; c0 = col - 1536; stride = 512; }
    else if (col < 3072) { src = Wmrg; c0 = col - 2048; stride = 1024; }
    else if (col < 3584) { src = Wrrg; c0 = col - 3072; stride = 512; }
    else if (col < 4608) { src = Wmwg; c0 = col - 3584; stride = 1024; }
    else                 { src = Wrwg; c0 = col - 4608; stride = 512; }
    const float4 v = *(const float4*)(src + (size_t)j * stride + c0);
    ushort4 u;
    u.x = __bfloat16_as_ushort(__float2bfloat16(v.x));
    u.y = __bfloat16_as_ushort(__float2bfloat16(v.y));
    u.z = __bfloat16_as_ushort(__float2bfloat16(v.z));
    u.w = __bfloat16_as_ushort(__float2bfloat16(v.w));
    *(ushort4*)(Wg7 + (size_t)j * WG7_STRIDE + col) = u;
  }
}

// ================= recurrence stage 1: gates (+P/E GEMM riders on first launch) =========
// blocks [0, pe_blocks): Pb = bf16(WhoB.Wdt^T) (128 blocks) then Eb = bf16(WencB.Wdt^T)
//                        (256 blocks); 64x64 tiles, full K=1024, double-buffered LDS,
//                        direct bf16 stores (no split-K, no atomics, no poison dependence)
// blocks [pe_blocks, pe_blocks+1024): per-row gates GEMV from bf16 Wg7 (row-packed)
__global__ __launch_bounds__(256) void gates_pe(
    const bf16* __restrict__ Wg7, const float* __restrict__ b_inp,
    const float* __restrict__ b_rinp, const float* __restrict__ b_ig,
    const float* __restrict__ b_mig, const float* __restrict__ b_rig,
    const float* __restrict__ b_rg, const float* __restrict__ b_mrg,
    const float* __restrict__ b_rrg, const float* __restrict__ b_wg,
    const float* __restrict__ b_mwg, const float* __restrict__ b_rwg,
    const float* __restrict__ out_s, const float* __restrict__ mem_s,
    float* __restrict__ rgm, float* __restrict__ h0v, float* __restrict__ wgv,
    const bf16* __restrict__ WhoB, const bf16* __restrict__ WencB,
    const bf16* __restrict__ Wdt, bf16* __restrict__ Pb, bf16* __restrict__ Eb,
    int pe_blocks) {
  __shared__ char smem[32768];  // dbuf: buf0 {A@0,B@8192}, buf1 {A@16384,B@24576}
  const int tid = threadIdx.x;
  if ((int)blockIdx.x >= pe_blocks) {
    // ---- gates GEMV path (bf16 weights, one contiguous 10KB row) ----
    float(*red)[4] = (float(*)[4])smem;
    const int j = blockIdx.x - pe_blocks, lane = tid & 63, wave = tid >> 6;
    const float4 z = make_float4(0.f, 0.f, 0.f, 0.f);
    const float4 o4 = (tid < 128) ? *(const float4*)(out_s + tid * 4) : z;
    const float4 m4 = *(const float4*)(mem_s + tid * 4);
    const bf16* rowb = Wg7 + (size_t)j * WG7_STRIDE;
    float p[7];
    p[0] = (tid < 128) ? dot4(b2f4(*(const ushort4*)(rowb + tid * 4)), o4) : 0.f;
    p[1] = dot4(b2f4(*(const ushort4*)(rowb + 512 + tid * 4)), m4);
    p[2] = (tid < 128) ? dot4(b2f4(*(const ushort4*)(rowb + 1536 + tid * 4)), o4) : 0.f;
    p[3] = dot4(b2f4(*(const ushort4*)(rowb + 2048 + tid * 4)), m4);
    p[4] = (tid < 128) ? dot4(b2f4(*(const ushort4*)(rowb + 3072 + tid * 4)), o4) : 0.f;
    p[5] = dot4(b2f4(*(const ushort4*)(rowb + 3584 + tid * 4)), m4);
    p[6] = (tid < 128) ? dot4(b2f4(*(const ushort4*)(rowb + 4608 + tid * 4)), o4) : 0.f;
#pragma unroll
    for (int d = 0; d < 7; ++d) {
      float s = wred(p[d]);
      if (lane == 0) red[d][wave] = s;
    }
    __syncthreads();
    if (tid == 0) {
      float D[7];
#pragma unroll
      for (int d = 0; d < 7; ++d) D[d] = red[d][0] + red[d][1] + red[d][2] + red[d][3];
      const float abi = b_inp[j] + b_rinp[j] + D[0];
      const float aig = b_ig[j] + b_mig[j] + b_rig[j] + D[1] + D[2];
      const float arg = b_rg[j] + b_mrg[j] + b_rrg[j] + D[3] + D[4];
      const float awg = b_wg[j] + b_mwg[j] + b_rwg[j] + D[5] + D[6];
      rgm[j] = fsig(arg) * mem_s[j];
      h0v[j] = fsig(abi) * fsig(aig);
      wgv[j] = fsig(awg);
    }
    return;
  }
  // ---- P/E GEMM path (first launch only), double-buffered ----
  const int bi = blockIdx.x;
  const bf16* Ag;
  bf16* Cg;
  int m0, n0;
  if (bi < 128) {
    Ag = WhoB; Cg = Pb;
    m0 = (bi >> 4) * 64; n0 = (bi & 15) * 64;
  } else {
    const int b2 = bi - 128;  // < 256
    Ag = WencB; Cg = Eb;
    m0 = (b2 >> 4) * 64; n0 = (b2 & 15) * 64;
  }
  const int wave = tid >> 6, lane = tid & 63;
  const int wm = wave >> 1, wn = wave & 1;
  f32x4 acc[2][2] = {};

  auto STAGE = [&](int kt, unsigned bofs) {
#pragma unroll
    for (int i = 0; i < 2; ++i) {
      const int ci = i * 256 + tid;
      const int row = ci >> 3, ck = (ci & 7) ^ (row & 7);
      const bf16* g = Ag + (size_t)(m0 + row) * 1024 + kt + ck * 8;
      const unsigned lofs =
          (unsigned)__builtin_amdgcn_readfirstlane(bofs + (i * 256 + wave * 64) * 16);
      __builtin_amdgcn_global_load_lds(
          (const __attribute__((address_space(1))) void*)g,
          (__attribute__((address_space(3))) void*)(smem + lofs), 16, 0, 0);
    }
#pragma unroll
    for (int i = 0; i < 2; ++i) {
      const int ci = i * 256 + tid;
      const int row = ci >> 3, ck = (ci & 7) ^ (row & 7);
      const bf16* g = Wdt + (size_t)(n0 + row) * 1024 + kt + ck * 8;
      const unsigned lofs =
          (unsigned)__builtin_amdgcn_readfirstlane(bofs + 8192 + (i * 256 + wave * 64) * 16);
      __builtin_amdgcn_global_load_lds(
          (const __attribute__((address_space(1))) void*)g,
          (__attribute__((address_space(3))) void*)(smem + lofs), 16, 0, 0);
    }
  };

  STAGE(0, 0);
  __syncthreads();
  unsigned cur = 0;
  for (int kt = 0; kt < 1024; kt += 64) {
    if (kt + 64 < 1024) STAGE(kt + 64, (cur ^ 1u) * 16384u);
#pragma unroll
    for (int ks = 0; ks < 2; ++ks) {
      const int ckk = ks * 4 + (lane >> 4);
      const unsigned cofs = cur * 16384u;
      s16x8 af[2];
#pragma unroll
      for (int i = 0; i < 2; ++i) {
        const int R = wm * 32 + i * 16 + (lane & 15);
        af[i] = *(const s16x8*)(smem + cofs + (R * 8 + (ckk ^ (R & 7))) * 16);
      }
#pragma unroll
      for (int j = 0; j < 2; ++j) {
        const int R = wn * 32 + j * 16 + (lane & 15);
        const s16x8 bfr = *(const s16x8*)(smem + cofs + 8192 + (R * 8 + (ckk ^ (R & 7))) * 16);
#pragma unroll
        for (int i = 0; i < 2; ++i)
          acc[i][j] = __builtin_amdgcn_mfma_f32_16x16x32_bf16(af[i], bfr, acc[i][j], 0, 0, 0);
      }
    }
    __syncthreads();  // drains vmcnt(0)+lgkmcnt(0): next-tile loads landed, all reads done
    cur ^= 1u;
  }
  const int mb = (lane >> 4) * 4, nb = lane & 15;
#pragma unroll
  for (int i = 0; i < 2; ++i) {
#pragma unroll
    for (int j = 0; j < 2; ++j) {
      const int col = n0 + wn * 32 + j * 16 + nb;
#pragma unroll
      for (int r = 0; r < 4; ++r) {
        const int rowg = m0 + wm * 32 + i * 16 + mb + r;
        Cg[(size_t)rowg * 1024 + col] = __float2bfloat16(acc[i][j][r]);
      }
    }
  }
}

// ================= recurrence stage 2: fused decode+update via E/P (all-bf16 reads) ======
// hid = b_dec + Wdec.rgm + h0v  (never materialized)
// mem' = (1-wg)mem + wg*tanh(b_enc + Web + E.rgm + Wenc.h0v)   [rows 0..1023]
// out' = vout + P.rgm + Who.h0v                                 [rows 1024..1535]
__global__ void step_fuse(const bf16* __restrict__ Eb, const bf16* __restrict__ WencB,
                          const bf16* __restrict__ Pb, const bf16* __restrict__ WhoB,
                          const float* __restrict__ b_enc, const float* __restrict__ Web,
                          const float* __restrict__ vout, const float* __restrict__ rgm,
                          const float* __restrict__ h0v, const float* __restrict__ wgv,
                          float* __restrict__ mem_s, float* __restrict__ out_s) {
  __shared__ float red[4];
  const int id = blockIdx.x, tid = threadIdx.x;
  const float4 r4 = *(const float4*)(rgm + tid * 4);
  const float4 h4 = *(const float4*)(h0v + tid * 4);
  const bf16* Ar = (id < 1024) ? (Eb + (size_t)id * 1024) : (Pb + (size_t)(id - 1024) * 1024);
  const bf16* Br =
      (id < 1024) ? (WencB + (size_t)id * 1024) : (WhoB + (size_t)(id - 1024) * 1024);
  const float4 a4 = b2f4(*(const ushort4*)(Ar + tid * 4));
  const float4 b4 = b2f4(*(const ushort4*)(Br + tid * 4));
  const float s = wred(dot4(a4, r4) + dot4(b4, h4));
  if ((tid & 63) == 0) red[tid >> 6] = s;
  __syncthreads();
  if (tid == 0) {
    const float d = red[0] + red[1] + red[2] + red[3];
    if (id < 1024) {
      const float wg = wgv[id];
      mem_s[id] = (1.0f - wg) * mem_s[id] + wg * ftanh(b_enc[id] + Web[id] + d);
    } else {
      out_s[id - 1024] = vout[id - 1024] + d;
    }
  }
}

// ================= step-4 constants + M1 scale =================
// [0,1024):    ccat = [c_bi|c_ig|c_rg]  (bf16 Wg7 weights)
// [1024,3072): Wcat2[:,1024:2048] = bf16(Pb * mem3)
__global__ void final_consts(const bf16* __restrict__ Wg7, const float* __restrict__ b_inp,
                             const float* __restrict__ b_rinp, const float* __restrict__ b_ig,
                             const float* __restrict__ b_mig, const float* __restrict__ b_rig,
                             const float* __restrict__ b_rg, const float* __restrict__ b_mrg,
                             const float* __restrict__ b_rrg, const float* __restrict__ out_s,
                             const float* __restrict__ mem_s, const bf16* __restrict__ Pb,
                             float* __restrict__ ccat, bf16* __restrict__ Wcat2) {
  __shared__ float red[5][4];
  const int id = blockIdx.x, tid = threadIdx.x, lane = tid & 63, wave = tid >> 6;
  if (id < 1024) {
    const float4 z = make_float4(0.f, 0.f, 0.f, 0.f);
    const float4 o4 = (tid < 128) ? *(const float4*)(out_s + tid * 4) : z;
    const float4 m4 = *(const float4*)(mem_s + tid * 4);
    const bf16* rowb = Wg7 + (size_t)id * WG7_STRIDE;
    float p[5];
    p[0] = (tid < 128) ? dot4(b2f4(*(const ushort4*)(rowb + tid * 4)), o4) : 0.f;
    p[1] = dot4(b2f4(*(const ushort4*)(rowb + 512 + tid * 4)), m4);
    p[2] = (tid < 128) ? dot4(b2f4(*(const ushort4*)(rowb + 1536 + tid * 4)), o4) : 0.f;
    p[3] = dot4(b2f4(*(const ushort4*)(rowb + 2048 + tid * 4)), m4);
    p[4] = (tid < 128) ? dot4(b2f4(*(const ushort4*)(rowb + 3072 + tid * 4)), o4) : 0.f;
#pragma unroll
    for (int d = 0; d < 5; ++d) {
      float s = wred(p[d]);
      if (lane == 0) red[d][wave] = s;
    }
    __syncthreads();
    if (tid == 0) {
      float D[5];
#pragma unroll
      for (int d = 0; d < 5; ++d) D[d] = red[d][0] + red[d][1] + red[d][2] + red[d][3];
      ccat[id] = b_inp[id] + b_rinp[id] + D[0];
      ccat[1024 + id] = b_ig[id] + b_mig[id] + b_rig[id] + D[1] + D[2];
      ccat[2048 + id] = b_rg[id] + b_mrg[id] + b_rrg[id] + D[3] + D[4];
    }
  } else {
    const int idx = (id - 1024) * 256 + tid;  // < 524288
    const int k = idx & 1023;
    const float pv = b2f(((const unsigned short*)Pb)[idx]);
    Wcat2[(size_t)(idx >> 10) * 2048 + 1024 + k] = __float2bfloat16(pv * mem_s[k]);
  }
}

// ================= gate GEMM: NG=3, 64x64 tile, BK=32 double-buffered @4 blocks/CU ======
// R5 lesson: dbuf must not cost occupancy. BK=32 halves per-buffer LDS (A 4KB + 3xB 12KB
// = 16KB/buf, 32KB total) so dbuf keeps 4 blocks/CU. Same bytes, same 192 MFMAs; the
// next-tile global->LDS latency now hides under current-tile MFMA. XCD swizzle kept.
__global__ __launch_bounds__(256, 4) void gemm_gates(const bf16* __restrict__ A,
                                                     const bf16* __restrict__ Wcat,
                                                     const float* __restrict__ ccat,
                                                     bf16* __restrict__ Hcat) {
  __shared__ char smem[32768];  // dbuf 16KB each: {A 4KB | B 3x4KB}
  const int tid = threadIdx.x, wave = tid >> 6, lane = tid & 63;
  const int wm = wave >> 1, wn = wave & 1;
  const int swz = (blockIdx.x & 7) * 128 + (blockIdx.x >> 3);
  const int m0 = (swz >> 4) * 64, n0 = (swz & 15) * 64;
  f32x4 acc[3][2][2] = {};

  // stage one BK=32 tile: per matrix 64 rows x 32 cols x 2B = 4KB = 256 lanes x 16B.
  // write swizzle: row = tid>>2, ck = (tid&3)^(row&3); LDS linear (wave base + lane*16).
  auto STAGE = [&](int kt, unsigned bofs) {
    const int row = tid >> 2, ck = (tid & 3) ^ (row & 3);
    {
      const bf16* g = A + (size_t)(m0 + row) * 512 + kt + ck * 8;
      const unsigned lofs = (unsigned)__builtin_amdgcn_readfirstlane(bofs + wave * 1024u);
      __builtin_amdgcn_global_load_lds(
          (const __attribute__((address_space(1))) void*)g,
          (__attribute__((address_space(3))) void*)(smem + lofs), 16, 0, 0);
    }
#pragma unroll
    for (int gI = 0; gI < 3; ++gI) {
      const bf16* g = Wcat + gI * 524288 + (size_t)(n0 + row) * 512 + kt + ck * 8;
      const unsigned lofs = (unsigned)__builtin_amdgcn_readfirstlane(
          bofs + 4096u + gI * 4096u + wave * 1024u);
      __builtin_amdgcn_global_load_lds(
          (const __attribute__((address_space(1))) void*)g,
          (__attribute__((address_space(3))) void*)(smem + lofs), 16, 0, 0);
    }
  };

  STAGE(0, 0);
  __syncthreads();
  unsigned cur = 0;
  for (int kt = 0; kt < 512; kt += 32) {
    if (kt + 32 < 512) STAGE(kt + 32, (cur ^ 1u) * 16384u);
    {
      const int ckk = lane >> 4;  // k-group within BK=32
      const unsigned cofs = cur * 16384u;
      s16x8 af[2];
#pragma unroll
      for (int i = 0; i < 2; ++i) {
        const int R = wm * 32 + i * 16 + (lane & 15);
        af[i] = *(const s16x8*)(smem + cofs + R * 64 + ((ckk ^ (R & 3)) * 16));
      }
#pragma unroll
      for (int gI = 0; gI < 3; ++gI) {
#pragma unroll
        for (int j = 0; j < 2; ++j) {
          const int R = wn * 32 + j * 16 + (lane & 15);
          const s16x8 bfr = *(const s16x8*)(smem + cofs + 4096 + gI * 4096 + R * 64 +
                                            ((ckk ^ (R & 3)) * 16));
#pragma unroll
          for (int i = 0; i < 2; ++i)
            acc[gI][i][j] =
                __builtin_amdgcn_mfma_f32_16x16x32_bf16(af[i], bfr, acc[gI][i][j], 0, 0, 0);
        }
      }
    }
    __syncthreads();  // drains vmcnt(0)+lgkmcnt(0)
    cur ^= 1u;
  }

  // epilogue: fast sigmoid -> LDS repack (stride 80 elems = 160B, 16B-aligned) -> 16B stores
  bf16* sm = (bf16*)smem;          // H0 tile [64][80]
  bf16* sr = (bf16*)smem + 5120;   // RG tile [64][80]
  const int mb = (lane >> 4) * 4, nb = lane & 15;
#pragma unroll
  for (int i = 0; i < 2; ++i) {
#pragma unroll
    for (int j = 0; j < 2; ++j) {
      const int colL = wn * 32 + j * 16 + nb;
      const int jg = n0 + colL;
      const float c0 = ccat[jg], c1 = ccat[1024 + jg], c2 = ccat[2048 + jg];
#pragma unroll
      for (int r = 0; r < 4; ++r) {
        const int rowL = wm * 32 + i * 16 + mb + r;
        const float h = fsig(acc[0][i][j][r] + c0) * fsig(acc[1][i][j][r] + c1);
        const float rg = fsig(acc[2][i][j][r] + c2);
        sm[rowL * 80 + colL] = __float2bfloat16(h);
        sr[rowL * 80 + colL] = __float2bfloat16(rg);
      }
    }
  }
  __syncthreads();
#pragma unroll
  for (int pp = 0; pp < 2; ++pp) {  // 64 rows x 8 chunks = 512 chunks per tile
    const int c = pp * 256 + tid;
    const int row = c >> 3, cc = c & 7;
    const s16x8 v0 = *(const s16x8*)(sm + row * 80 + cc * 8);
    const s16x8 v1 = *(const s16x8*)(sr + row * 80 + cc * 8);
    *(s16x8*)(Hcat + (size_t)(m0 + row) * 2048 + n0 + cc * 8) = v0;
    *(s16x8*)(Hcat + (size_t)(m0 + row) * 2048 + 1024 + n0 + cc * 8) = v1;
  }
}

// ================= out GEMM: 64x64, K=2048, double-buffered, direct store + vout[col] =====
// 1D grid 512 + XCD swizzle: each XCD owns m-panels [8x,8x+8) with all 8 n-tiles ->
// per-XCD working set = A 8x256KB = 2MB + B 2MB fits 4MB L2.
__global__ __launch_bounds__(256, 4) void gemm_out(const bf16* __restrict__ A,
                                                   const bf16* __restrict__ Bp,
                                                   const float* __restrict__ vout,
                                                   float* __restrict__ outF) {
  __shared__ char smem[32768];  // dbuf: buf0 {A@0,B@8192}, buf1 {A@16384,B@24576}
  const int tid = threadIdx.x, wave = tid >> 6, lane = tid & 63;
  const int wm = wave >> 1, wn = wave & 1;
  const int swz = (blockIdx.x & 7) * 64 + (blockIdx.x >> 3);
  const int m0 = (swz >> 3) * 64, n0 = (swz & 7) * 64;
  f32x4 acc[2][2] = {};

  auto STAGE = [&](int kt, unsigned bofs) {
#pragma unroll
    for (int i = 0; i < 2; ++i) {
      const int ci = i * 256 + tid;
      const int row = ci >> 3, ck = (ci & 7) ^ (row & 7);
      const bf16* g = A + (size_t)(m0 + row) * 2048 + kt + ck * 8;
      const unsigned lofs =
          (unsigned)__builtin_amdgcn_readfirstlane(bofs + (i * 256 + wave * 64) * 16);
      __builtin_amdgcn_global_load_lds(
          (const __attribute__((address_space(1))) void*)g,
          (__attribute__((address_space(3))) void*)(smem + lofs), 16, 0, 0);
    }
#pragma unroll
    for (int i = 0; i < 2; ++i) {
      const int ci = i * 256 + tid;
      const int row = ci >> 3, ck = (ci & 7) ^ (row & 7);
      const bf16* g = Bp + (size_t)(n0 + row) * 2048 + kt + ck * 8;
      const unsigned lofs =
          (unsigned)__builtin_amdgcn_readfirstlane(bofs + 8192 + (i * 256 + wave * 64) * 16);
      __builtin_amdgcn_global_load_lds(
          (const __attribute__((address_space(1))) void*)g,
          (__attribute__((address_space(3))) void*)(smem + lofs), 16, 0, 0);
    }
  };

  STAGE(0, 0);
  __syncthreads();
  unsigned cur = 0;
  for (int kt = 0; kt < 2048; kt += 64) {
    if (kt + 64 < 2048) STAGE(kt + 64, (cur ^ 1u) * 16384u);
#pragma unroll
    for (int ks = 0; ks < 2; ++ks) {
      const int ckk = ks * 4 + (lane >> 4);
      const unsigned cofs = cur * 16384u;
      s16x8 af[2];
#pragma unroll
      for (int i = 0; i < 2; ++i) {
        const int R = wm * 32 + i * 16 + (lane & 15);
        af[i] = *(const s16x8*)(smem + cofs + (R * 8 + (ckk ^ (R & 7))) * 16);
      }
#pragma unroll
      for (int j = 0; j < 2; ++j) {
        const int R = wn * 32 + j * 16 + (lane & 15);
        const s16x8 bfr = *(const s16x8*)(smem + cofs + 8192 + (R * 8 + (ckk ^ (R & 7))) * 16);
#pragma unroll
        for (int i = 0; i < 2; ++i)
          acc[i][j] = __builtin_amdgcn_mfma_f32_16x16x32_bf16(af[i], bfr, acc[i][j], 0, 0, 0);
      }
    }
    __syncthreads();  // drains vmcnt(0)+lgkmcnt(0): next-tile loads landed, all reads done
    cur ^= 1u;
  }

  const int mb = (lane >> 4) * 4, nb = lane & 15;
#pragma unroll
  for (int i = 0; i < 2; ++i) {
#pragma unroll
    for (int j = 0; j < 2; ++j) {
      const int col = n0 + wn * 32 + j * 16 + nb;
#pragma unroll
      for (int r = 0; r < 4; ++r) {
        const int rowg = m0 + wm * 32 + i * 16 + mb + r;
        outF[(size_t)rowg * 512 + col] = acc[i][j][r] + vout[col];
      }
    }
  }
}

extern "C" void kernel_launch(void* const* d_in, const int* in_sizes, int n_in, void* d_out,
                              int out_size, void* d_ws, size_t ws_size, hipStream_t stream) {
  const float* input  = (const float*)d_in[0];
  const float* W_ig   = (const float*)d_in[1];  const float* b_ig   = (const float*)d_in[2];
  const float* W_rig  = (const float*)d_in[3];  const float* b_rig  = (const float*)d_in[4];
  const float* W_mig  = (const float*)d_in[5];  const float* b_mig  = (const float*)d_in[6];
  const float* W_inp  = (const float*)d_in[7];  const float* b_inp  = (const float*)d_in[8];
  const float* W_rinp = (const float*)d_in[9];  const float* b_rinp = (const float*)d_in[10];
  const float* W_rg   = (const float*)d_in[11]; const float* b_rg   = (const float*)d_in[12];
  const float* W_rrg  = (const float*)d_in[13]; const float* b_rrg  = (const float*)d_in[14];
  const float* W_mrg  = (const float*)d_in[15]; const float* b_mrg  = (const float*)d_in[16];
  const float* W_dec  = (const float*)d_in[17]; const float* b_dec  = (const float*)d_in[18];
  const float* W_wg   = (const float*)d_in[19]; const float* b_wg   = (const float*)d_in[20];
  const float* W_rwg  = (const float*)d_in[21]; const float* b_rwg  = (const float*)d_in[22];
  const float* W_mwg  = (const float*)d_in[23]; const float* b_mwg  = (const float*)d_in[24];
  const float* W_enc  = (const float*)d_in[25]; const float* b_enc  = (const float*)d_in[26];
  const float* W_ho   = (const float*)d_in[27];
  (void)W_wg;  // input-side write gate weight: dead (x=0 in steps 0-3; step-4 write gate dead)

  char* ws = (char*)d_ws;
  float* out_s = (float*)(ws + 0);
  float* mem_s = (float*)(ws + 4096);
  float* rgm   = (float*)(ws + 8192);
  float* h0v   = (float*)(ws + 12288);
  float* wgv   = (float*)(ws + 16384);
  float* ccat  = (float*)(ws + 24576);   // 3072 f32
  float* vout  = (float*)(ws + 40960);   // 512 f32
  float* Web   = (float*)(ws + 45056);   // 1024 f32 (Wenc . b_dec)
  bf16* Pb     = (bf16*)(ws + 65536);                  // [512][1024] bf16 (1MB, direct store)
  bf16* Xb     = (bf16*)(ws + 2162688);                // [4096][512] (4MB)
  bf16* Wcat   = (bf16*)(ws + 6356992);                // [3072][512] (3MB)
  bf16* WhoB   = (bf16*)(ws + 9502720);                // [512][1024] (1MB)
  bf16* Wcat2  = (bf16*)(ws + 10551296);               // [512][2048] (2MB)
  bf16* Wdt    = (bf16*)(ws + 12648448);               // [1024][1024] (2MB)
  bf16* Hcat   = (bf16*)(ws + 14745600);               // [4096][2048] (16MB)
  bf16* Eb     = (bf16*)(ws + 31522816);               // [1024][1024] bf16 (2MB, direct store)
  bf16* WencB  = (bf16*)(ws + 35717120);               // [1024][1024] (2MB)
  bf16* Wg7    = (bf16*)(ws + 37814272);               // [1024][5120] bf16 (10.5MB)

  // setup: casts + transposes + vout/Web + inline step-0 update + Wg7 cast
  setup<<<23552, 256, 0, stream>>>(W_inp, W_ig, W_rg, W_ho, W_dec, W_enc, input,
                                   W_rinp, W_mig, W_rig, W_mrg, W_rrg, W_mwg, W_rwg,
                                   b_inp, b_rinp, b_ig, b_mig, b_rig, b_wg, b_mwg, b_rwg,
                                   b_dec, b_enc, Wcat, WhoB, Wcat2, Wdt, WencB, Xb,
                                   out_s, mem_s, vout, Web, Wg7);

  // steps 1..3: gates (+P/E GEMM riders on first launch) -> fused decode+update
  for (int s = 0; s < 3; ++s) {
    const int pe = (s == 0) ? 384 : 0;
    gates_pe<<<1024 + pe, 256, 0, stream>>>(Wg7, b_inp, b_rinp, b_ig, b_mig, b_rig, b_rg, b_mrg,
                                            b_rrg, b_wg, b_mwg, b_rwg, out_s, mem_s, rgm, h0v,
                                            wgv, WhoB, WencB, Wdt, Pb, Eb, pe);
    step_fuse<<<1536, 256, 0, stream>>>(Eb, WencB, Pb, WhoB, b_enc, Web, vout, rgm, h0v, wgv,
                                        mem_s, out_s);
  }

  // step-4 constants (ccat) + Wcat2 right half = bf16(Pb * mem3)
  final_consts<<<3072, 256, 0, stream>>>(Wg7, b_inp, b_rinp, b_ig, b_mig, b_rig, b_rg, b_mrg,
                                         b_rrg, out_s, mem_s, Pb, ccat, Wcat2);

  // gates: Hcat = [sig*sig | sig] of Xb . [Wi|Wg|Wr]^T + ccat
  gemm_gates<<<1024, 256, 0, stream>>>(Xb, Wcat, ccat, Hcat);

  // out = [H0|rg] . [Who|M1]^T + vout  (direct store)
  gemm_out<<<512, 256, 0, stream>>>(Hcat, Wcat2, vout, (float*)d_out);
}

// Round 8
// 216.512 us; speedup vs baseline: 1.0121x; 1.0121x over previous
//
#include <hip/hip_runtime.h>
#include <hip/hip_bf16.h>
#include <math.h>

typedef __hip_bfloat16 bf16;
typedef __attribute__((ext_vector_type(8))) short s16x8;   // 8 bf16 (4 VGPRs)
typedef __attribute__((ext_vector_type(4))) float f32x4;

__device__ __forceinline__ float fsig(float x) {
  return __builtin_amdgcn_rcpf(1.0f + __expf(-x));
}
__device__ __forceinline__ float ftanh(float x) { return 2.0f * fsig(2.0f * x) - 1.0f; }
__device__ __forceinline__ float dot4(float4 a, float4 b) {
  return a.x * b.x + a.y * b.y + a.z * b.z + a.w * b.w;
}
__device__ __forceinline__ float wred(float s) {
#pragma unroll
  for (int off = 32; off > 0; off >>= 1) s += __shfl_down(s, off, 64);
  return s;
}
__device__ __forceinline__ float b2f(unsigned short u) {
  return __uint_as_float((unsigned)u << 16);
}
__device__ __forceinline__ float4 b2f4(ushort4 u) {
  return make_float4(b2f(u.x), b2f(u.y), b2f(u.z), b2f(u.w));
}

// Wg7 row layout (bf16, 5120 per row): [Wri 0 | Wmig 512 | Wrig 1536 | Wmrg 2048 |
//                                       Wrrg 3072 | Wmwg 3584 | Wrwg 4608]
#define WG7_STRIDE 5120

// ================= setup mega-kernel =================
// [0,12288):     cast Wcat ([Winp|Wig|Wrg]), WhoB + Wcat2-left, WencB
// [12288,14336): transpose input [512][4096] f32 -> Xb [4096][512] bf16
// [14336,15360): Wdt[k][j] = bf16(W_dec[j][k])
// [15360,16896): vout[o] = Who[o,:].b_dec (o<512) ; Web[o-512] = Wenc[o-512,:].b_dec
// [16896,18432): step-0 update inline: hidv closed-form from biases (mem0=0, no mem read)
// [18432,23552): cast 7 gate-weight matrices into row-packed bf16 Wg7[1024][5120]
__global__ void setup(const float* __restrict__ W_inp, const float* __restrict__ W_ig,
                      const float* __restrict__ W_rg, const float* __restrict__ W_ho,
                      const float* __restrict__ W_dec, const float* __restrict__ W_enc,
                      const float* __restrict__ input,
                      const float* __restrict__ Wri, const float* __restrict__ Wmig,
                      const float* __restrict__ Wrig, const float* __restrict__ Wmrg,
                      const float* __restrict__ Wrrg, const float* __restrict__ Wmwg,
                      const float* __restrict__ Wrwg,
                      const float* __restrict__ b_inp, const float* __restrict__ b_rinp,
                      const float* __restrict__ b_ig, const float* __restrict__ b_mig,
                      const float* __restrict__ b_rig, const float* __restrict__ b_wg,
                      const float* __restrict__ b_mwg, const float* __restrict__ b_rwg,
                      const float* __restrict__ b_dec, const float* __restrict__ b_enc,
                      bf16* __restrict__ Wcat,
                      bf16* __restrict__ WhoB, bf16* __restrict__ Wcat2, bf16* __restrict__ Wdt,
                      bf16* __restrict__ WencB, bf16* __restrict__ Xb,
                      float* __restrict__ out_s, float* __restrict__ mem_s,
                      float* __restrict__ vout, float* __restrict__ Web,
                      bf16* __restrict__ Wg7) {
  __shared__ float t[32][33];
  const int id = blockIdx.x, tid = threadIdx.x;
  if (id < 12288) {
    const int i = id * 256 + tid;  // < 3145728
    if (i < 524288) {
      Wcat[i] = __float2bfloat16(W_inp[i]);
    } else if (i < 1048576) {
      Wcat[i] = __float2bfloat16(W_ig[i - 524288]);
    } else if (i < 1572864) {
      Wcat[i] = __float2bfloat16(W_rg[i - 1048576]);
    } else if (i < 2097152) {
      const int k = i - 1572864;
      const bf16 vv = __float2bfloat16(W_ho[k]);
      WhoB[k] = vv;
      Wcat2[(size_t)(k >> 10) * 2048 + (k & 1023)] = vv;
    } else {
      const int k = i - 2097152;  // < 1048576
      WencB[k] = __float2bfloat16(W_enc[k]);
    }
  } else if (id < 14336) {
    const int b = id - 12288;
    const int i0 = (b >> 7) * 32, b0 = (b & 127) * 32;
    const int tx = tid & 31, ty = tid >> 5;
#pragma unroll
    for (int r = ty; r < 32; r += 8) t[r][tx] = input[(size_t)(i0 + r) * 4096 + b0 + tx];
    __syncthreads();
#pragma unroll
    for (int r = ty; r < 32; r += 8)
      Xb[(size_t)(b0 + r) * 512 + i0 + tx] = __float2bfloat16(t[tx][r]);
  } else if (id < 15360) {
    const int b = id - 14336;
    const int j0 = (b >> 5) * 32, k0 = (b & 31) * 32;
    const int tx = tid & 31, ty = tid >> 5;
#pragma unroll
    for (int r = ty; r < 32; r += 8) t[r][tx] = W_dec[(size_t)(j0 + r) * 1024 + k0 + tx];
    __syncthreads();
#pragma unroll
    for (int r = ty; r < 32; r += 8)
      Wdt[(size_t)(k0 + r) * 1024 + j0 + tx] = __float2bfloat16(t[tx][r]);
  } else if (id < 16896) {
    const int o = id - 15360;  // < 1536
    const float* row = (o < 512) ? (W_ho + (size_t)o * 1024) : (W_enc + (size_t)(o - 512) * 1024);
    const float4 a = *(const float4*)(row + tid * 4);
    const float4 b = *(const float4*)(b_dec + tid * 4);
    float s = wred(dot4(a, b));
    if ((tid & 63) == 0) t[0][tid >> 6] = s;
    __syncthreads();
    if (tid == 0) {
      const float d = t[0][0] + t[0][1] + t[0][2] + t[0][3];
      if (o < 512) vout[o] = d;
      else Web[o - 512] = d;
    }
  } else if (id < 18432) {
    const int id2 = id - 16896;  // < 1536
    const float4 bd = *(const float4*)(b_dec + tid * 4);
    const float4 v1 = *(const float4*)(b_inp + tid * 4);
    const float4 v2 = *(const float4*)(b_rinp + tid * 4);
    const float4 v3 = *(const float4*)(b_ig + tid * 4);
    const float4 v4 = *(const float4*)(b_mig + tid * 4);
    const float4 v5 = *(const float4*)(b_rig + tid * 4);
    float4 hv;
    hv.x = bd.x + fsig(v1.x + v2.x) * fsig(v3.x + v4.x + v5.x);
    hv.y = bd.y + fsig(v1.y + v2.y) * fsig(v3.y + v4.y + v5.y);
    hv.z = bd.z + fsig(v1.z + v2.z) * fsig(v3.z + v4.z + v5.z);
    hv.w = bd.w + fsig(v1.w + v2.w) * fsig(v3.w + v4.w + v5.w);
    const float* row =
        (id2 < 1024) ? (W_enc + (size_t)id2 * 1024) : (W_ho + (size_t)(id2 - 1024) * 1024);
    float s = wred(dot4(*(const float4*)(row + tid * 4), hv));
    if ((tid & 63) == 0) t[0][tid >> 6] = s;
    __syncthreads();
    if (tid == 0) {
      const float d = t[0][0] + t[0][1] + t[0][2] + t[0][3];
      if (id2 < 1024) {
        const float wg = fsig(b_wg[id2] + b_mwg[id2] + b_rwg[id2]);
        mem_s[id2] = wg * ftanh(b_enc[id2] + d);  // mem0 == 0: no mem_s read
      } else {
        out_s[id2 - 1024] = d;
      }
    }
  } else {
    // ---- Wg7 cast: block handles 1024 elems of row j, fifth f ----
    const int b = id - 18432;  // < 5120
    const int j = b / 5, f = b - j * 5;
    const int col = f * 1024 + tid * 4;
    const float* src;
    int c0, stride;
    if (col < 512)       { src = Wri;  c0 = col;        stride = 512; }
    else if (col < 1536) { src = Wmig; c0 = col - 512;  stride = 1024; }
    else if (col < 2048) { src = Wrig; c0 = col - 1536; stride = 512; }
    else if (col < 3072) { src = Wmrg; c0 = col - 2048; stride = 1024; }
    else if (col < 3584) { src = Wrrg; c0 = col - 3072; stride = 512; }
    else if (col < 4608) { src = Wmwg; c0 = col - 3584; stride = 1024; }
    else                 { src = Wrwg; c0 = col - 4608; stride = 512; }
    const float4 v = *(const float4*)(src + (size_t)j * stride + c0);
    ushort4 u;
    u.x = __bfloat16_as_ushort(__float2bfloat16(v.x));
    u.y = __bfloat16_as_ushort(__float2bfloat16(v.y));
    u.z = __bfloat16_as_ushort(__float2bfloat16(v.z));
    u.w = __bfloat16_as_ushort(__float2bfloat16(v.w));
    *(ushort4*)(Wg7 + (size_t)j * WG7_STRIDE + col) = u;
  }
}

// ================= recurrence stage 1: gates (+P/E GEMM riders on first launch) =========
// blocks [0,128):   P = bf16(WhoB.Wdt^T) stored DIRECTLY into Wcat2[:,1024:2048]
// blocks [128,384): Eb = bf16(WencB.Wdt^T)
//                   64x64 tiles, full K=1024, double-buffered LDS, direct bf16 stores
// blocks [pe_blocks, pe_blocks+1024): per-row gates GEMV from bf16 Wg7 (row-packed)
__global__ __launch_bounds__(256) void gates_pe(
    const bf16* __restrict__ Wg7, const float* __restrict__ b_inp,
    const float* __restrict__ b_rinp, const float* __restrict__ b_ig,
    const float* __restrict__ b_mig, const float* __restrict__ b_rig,
    const float* __restrict__ b_rg, const float* __restrict__ b_mrg,
    const float* __restrict__ b_rrg, const float* __restrict__ b_wg,
    const float* __restrict__ b_mwg, const float* __restrict__ b_rwg,
    const float* __restrict__ out_s, const float* __restrict__ mem_s,
    float* __restrict__ rgm, float* __restrict__ h0v, float* __restrict__ wgv,
    const bf16* __restrict__ WhoB, const bf16* __restrict__ WencB,
    const bf16* __restrict__ Wdt, bf16* __restrict__ Wcat2, bf16* __restrict__ Eb,
    int pe_blocks) {
  __shared__ char smem[32768];  // dbuf: buf0 {A@0,B@8192}, buf1 {A@16384,B@24576}
  const int tid = threadIdx.x;
  if ((int)blockIdx.x >= pe_blocks) {
    // ---- gates GEMV path (bf16 weights, one contiguous 10KB row) ----
    float(*red)[4] = (float(*)[4])smem;
    const int j = blockIdx.x - pe_blocks, lane = tid & 63, wave = tid >> 6;
    const float4 z = make_float4(0.f, 0.f, 0.f, 0.f);
    const float4 o4 = (tid < 128) ? *(const float4*)(out_s + tid * 4) : z;
    const float4 m4 = *(const float4*)(mem_s + tid * 4);
    const bf16* rowb = Wg7 + (size_t)j * WG7_STRIDE;
    float p[7];
    p[0] = (tid < 128) ? dot4(b2f4(*(const ushort4*)(rowb + tid * 4)), o4) : 0.f;
    p[1] = dot4(b2f4(*(const ushort4*)(rowb + 512 + tid * 4)), m4);
    p[2] = (tid < 128) ? dot4(b2f4(*(const ushort4*)(rowb + 1536 + tid * 4)), o4) : 0.f;
    p[3] = dot4(b2f4(*(const ushort4*)(rowb + 2048 + tid * 4)), m4);
    p[4] = (tid < 128) ? dot4(b2f4(*(const ushort4*)(rowb + 3072 + tid * 4)), o4) : 0.f;
    p[5] = dot4(b2f4(*(const ushort4*)(rowb + 3584 + tid * 4)), m4);
    p[6] = (tid < 128) ? dot4(b2f4(*(const ushort4*)(rowb + 4608 + tid * 4)), o4) : 0.f;
#pragma unroll
    for (int d = 0; d < 7; ++d) {
      float s = wred(p[d]);
      if (lane == 0) red[d][wave] = s;
    }
    __syncthreads();
    if (tid == 0) {
      float D[7];
#pragma unroll
      for (int d = 0; d < 7; ++d) D[d] = red[d][0] + red[d][1] + red[d][2] + red[d][3];
      const float abi = b_inp[j] + b_rinp[j] + D[0];
      const float aig = b_ig[j] + b_mig[j] + b_rig[j] + D[1] + D[2];
      const float arg = b_rg[j] + b_mrg[j] + b_rrg[j] + D[3] + D[4];
      const float awg = b_wg[j] + b_mwg[j] + b_rwg[j] + D[5] + D[6];
      rgm[j] = fsig(arg) * mem_s[j];
      h0v[j] = fsig(abi) * fsig(aig);
      wgv[j] = fsig(awg);
    }
    return;
  }
  // ---- P/E GEMM path (first launch only), double-buffered ----
  const int bi = blockIdx.x;
  const bf16* Ag;
  bf16* Cg;
  int m0, n0, cstride;
  if (bi < 128) {
    Ag = WhoB; Cg = Wcat2 + 1024; cstride = 2048;  // P -> Wcat2 right half
    m0 = (bi >> 4) * 64; n0 = (bi & 15) * 64;
  } else {
    const int b2 = bi - 128;  // < 256
    Ag = WencB; Cg = Eb; cstride = 1024;
    m0 = (b2 >> 4) * 64; n0 = (b2 & 15) * 64;
  }
  const int wave = tid >> 6, lane = tid & 63;
  const int wm = wave >> 1, wn = wave & 1;
  f32x4 acc[2][2] = {};

  auto STAGE = [&](int kt, unsigned bofs) {
#pragma unroll
    for (int i = 0; i < 2; ++i) {
      const int ci = i * 256 + tid;
      const int row = ci >> 3, ck = (ci & 7) ^ (row & 7);
      const bf16* g = Ag + (size_t)(m0 + row) * 1024 + kt + ck * 8;
      const unsigned lofs =
          (unsigned)__builtin_amdgcn_readfirstlane(bofs + (i * 256 + wave * 64) * 16);
      __builtin_amdgcn_global_load_lds(
          (const __attribute__((address_space(1))) void*)g,
          (__attribute__((address_space(3))) void*)(smem + lofs), 16, 0, 0);
    }
#pragma unroll
    for (int i = 0; i < 2; ++i) {
      const int ci = i * 256 + tid;
      const int row = ci >> 3, ck = (ci & 7) ^ (row & 7);
      const bf16* g = Wdt + (size_t)(n0 + row) * 1024 + kt + ck * 8;
      const unsigned lofs =
          (unsigned)__builtin_amdgcn_readfirstlane(bofs + 8192 + (i * 256 + wave * 64) * 16);
      __builtin_amdgcn_global_load_lds(
          (const __attribute__((address_space(1))) void*)g,
          (__attribute__((address_space(3))) void*)(smem + lofs), 16, 0, 0);
    }
  };

  STAGE(0, 0);
  __syncthreads();
  unsigned cur = 0;
  for (int kt = 0; kt < 1024; kt += 64) {
    if (kt + 64 < 1024) STAGE(kt + 64, (cur ^ 1u) * 16384u);
#pragma unroll
    for (int ks = 0; ks < 2; ++ks) {
      const int ckk = ks * 4 + (lane >> 4);
      const unsigned cofs = cur * 16384u;
      s16x8 af[2];
#pragma unroll
      for (int i = 0; i < 2; ++i) {
        const int R = wm * 32 + i * 16 + (lane & 15);
        af[i] = *(const s16x8*)(smem + cofs + (R * 8 + (ckk ^ (R & 7))) * 16);
      }
#pragma unroll
      for (int j = 0; j < 2; ++j) {
        const int R = wn * 32 + j * 16 + (lane & 15);
        const s16x8 bfr = *(const s16x8*)(smem + cofs + 8192 + (R * 8 + (ckk ^ (R & 7))) * 16);
#pragma unroll
        for (int i = 0; i < 2; ++i)
          acc[i][j] = __builtin_amdgcn_mfma_f32_16x16x32_bf16(af[i], bfr, acc[i][j], 0, 0, 0);
      }
    }
    __syncthreads();  // drains vmcnt(0)+lgkmcnt(0): next-tile loads landed, all reads done
    cur ^= 1u;
  }
  const int mb = (lane >> 4) * 4, nb = lane & 15;
#pragma unroll
  for (int i = 0; i < 2; ++i) {
#pragma unroll
    for (int j = 0; j < 2; ++j) {
      const int col = n0 + wn * 32 + j * 16 + nb;
#pragma unroll
      for (int r = 0; r < 4; ++r) {
        const int rowg = m0 + wm * 32 + i * 16 + mb + r;
        Cg[(size_t)rowg * cstride + col] = __float2bfloat16(acc[i][j][r]);
      }
    }
  }
}

// ================= recurrence stage 2: fused decode+update via E/P (all-bf16 reads) ======
// hid = b_dec + Wdec.rgm + h0v  (never materialized)
// mem' = (1-wg)mem + wg*tanh(b_enc + Web + E.rgm + Wenc.h0v)   [rows 0..1023]
// out' = vout + P.rgm + Who.h0v                                 [rows 1024..1535]
// P rows live in Wcat2[:,1024:2048] (stride 2048).
__global__ void step_fuse(const bf16* __restrict__ Eb, const bf16* __restrict__ WencB,
                          const bf16* __restrict__ Wcat2, const bf16* __restrict__ WhoB,
                          const float* __restrict__ b_enc, const float* __restrict__ Web,
                          const float* __restrict__ vout, const float* __restrict__ rgm,
                          const float* __restrict__ h0v, const float* __restrict__ wgv,
                          float* __restrict__ mem_s, float* __restrict__ out_s) {
  __shared__ float red[4];
  const int id = blockIdx.x, tid = threadIdx.x;
  const float4 r4 = *(const float4*)(rgm + tid * 4);
  const float4 h4 = *(const float4*)(h0v + tid * 4);
  const bf16* Ar = (id < 1024) ? (Eb + (size_t)id * 1024)
                               : (Wcat2 + (size_t)(id - 1024) * 2048 + 1024);
  const bf16* Br =
      (id < 1024) ? (WencB + (size_t)id * 1024) : (WhoB + (size_t)(id - 1024) * 1024);
  const float4 a4 = b2f4(*(const ushort4*)(Ar + tid * 4));
  const float4 b4 = b2f4(*(const ushort4*)(Br + tid * 4));
  const float s = wred(dot4(a4, r4) + dot4(b4, h4));
  if ((tid & 63) == 0) red[tid >> 6] = s;
  __syncthreads();
  if (tid == 0) {
    const float d = red[0] + red[1] + red[2] + red[3];
    if (id < 1024) {
      const float wg = wgv[id];
      mem_s[id] = (1.0f - wg) * mem_s[id] + wg * ftanh(b_enc[id] + Web[id] + d);
    } else {
      out_s[id - 1024] = vout[id - 1024] + d;
    }
  }
}

// ================= step-4 constants: ccat = [c_bi|c_ig|c_rg] (bf16 Wg7 weights) =========
// (Wcat2-scale eliminated: rg*mem3 is folded into gemm_gates' epilogue instead.)
__global__ void final_consts(const bf16* __restrict__ Wg7, const float* __restrict__ b_inp,
                             const float* __restrict__ b_rinp, const float* __restrict__ b_ig,
                             const float* __restrict__ b_mig, const float* __restrict__ b_rig,
                             const float* __restrict__ b_rg, const float* __restrict__ b_mrg,
                             const float* __restrict__ b_rrg, const float* __restrict__ out_s,
                             const float* __restrict__ mem_s, float* __restrict__ ccat) {
  __shared__ float red[5][4];
  const int id = blockIdx.x, tid = threadIdx.x, lane = tid & 63, wave = tid >> 6;
  const float4 z = make_float4(0.f, 0.f, 0.f, 0.f);
  const float4 o4 = (tid < 128) ? *(const float4*)(out_s + tid * 4) : z;
  const float4 m4 = *(const float4*)(mem_s + tid * 4);
  const bf16* rowb = Wg7 + (size_t)id * WG7_STRIDE;
  float p[5];
  p[0] = (tid < 128) ? dot4(b2f4(*(const ushort4*)(rowb + tid * 4)), o4) : 0.f;
  p[1] = dot4(b2f4(*(const ushort4*)(rowb + 512 + tid * 4)), m4);
  p[2] = (tid < 128) ? dot4(b2f4(*(const ushort4*)(rowb + 1536 + tid * 4)), o4) : 0.f;
  p[3] = dot4(b2f4(*(const ushort4*)(rowb + 2048 + tid * 4)), m4);
  p[4] = (tid < 128) ? dot4(b2f4(*(const ushort4*)(rowb + 3072 + tid * 4)), o4) : 0.f;
#pragma unroll
  for (int d = 0; d < 5; ++d) {
    float s = wred(p[d]);
    if (lane == 0) red[d][wave] = s;
  }
  __syncthreads();
  if (tid == 0) {
    float D[5];
#pragma unroll
    for (int d = 0; d < 5; ++d) D[d] = red[d][0] + red[d][1] + red[d][2] + red[d][3];
    ccat[id] = b_inp[id] + b_rinp[id] + D[0];
    ccat[1024 + id] = b_ig[id] + b_mig[id] + b_rig[id] + D[1] + D[2];
    ccat[2048 + id] = b_rg[id] + b_mrg[id] + b_rrg[id] + D[3] + D[4];
  }
}

// ================= gate GEMM: NG=3, 64x64 tile, fused sigmoid + H0 product =================
// Measured-best form (R4/R6): single-buffered BK=64 @4 blocks/CU. Probes: dbuf@2blk/CU
// -5us (R5); dbuf@4blk/BK32 null (R7). Loads are L2/L3-served and hidden by TLP.
// Epilogue folds mem3 into rg (rg*mem3 -> Hcat right), eliminating the M1 buffer.
__global__ __launch_bounds__(256, 4) void gemm_gates(const bf16* __restrict__ A,
                                                     const bf16* __restrict__ Wcat,
                                                     const float* __restrict__ ccat,
                                                     const float* __restrict__ mem_s,
                                                     bf16* __restrict__ Hcat) {
  __shared__ char smem[32768];  // A tile 8KB @0; B_g tile 8KB @ 8192+g*8192
  const int tid = threadIdx.x, wave = tid >> 6, lane = tid & 63;
  const int wm = wave >> 1, wn = wave & 1;
  const int swz = (blockIdx.x & 7) * 128 + (blockIdx.x >> 3);
  const int m0 = (swz >> 4) * 64, n0 = (swz & 15) * 64;
  f32x4 acc[3][2][2] = {};

  for (int kt = 0; kt < 512; kt += 64) {
    __syncthreads();
#pragma unroll
    for (int i = 0; i < 2; ++i) {
      const int ci = i * 256 + tid;
      const int row = ci >> 3, ck = (ci & 7) ^ (row & 7);
      const bf16* g = A + (size_t)(m0 + row) * 512 + kt + ck * 8;
      const unsigned lofs = (unsigned)__builtin_amdgcn_readfirstlane((i * 256 + wave * 64) * 16);
      __builtin_amdgcn_global_load_lds(
          (const __attribute__((address_space(1))) void*)g,
          (__attribute__((address_space(3))) void*)(smem + lofs), 16, 0, 0);
    }
#pragma unroll
    for (int gI = 0; gI < 3; ++gI) {
      const bf16* Bp = Wcat + gI * 524288;
#pragma unroll
      for (int i = 0; i < 2; ++i) {
        const int ci = i * 256 + tid;
        const int row = ci >> 3, ck = (ci & 7) ^ (row & 7);
        const bf16* g = Bp + (size_t)(n0 + row) * 512 + kt + ck * 8;
        const unsigned lofs = (unsigned)__builtin_amdgcn_readfirstlane(
            8192 + gI * 8192 + (i * 256 + wave * 64) * 16);
        __builtin_amdgcn_global_load_lds(
            (const __attribute__((address_space(1))) void*)g,
            (__attribute__((address_space(3))) void*)(smem + lofs), 16, 0, 0);
      }
    }
    __syncthreads();

#pragma unroll
    for (int ks = 0; ks < 2; ++ks) {
      const int ckk = ks * 4 + (lane >> 4);
      s16x8 af[2];
#pragma unroll
      for (int i = 0; i < 2; ++i) {
        const int R = wm * 32 + i * 16 + (lane & 15);
        af[i] = *(const s16x8*)(smem + (R * 8 + (ckk ^ (R & 7))) * 16);
      }
#pragma unroll
      for (int gI = 0; gI < 3; ++gI) {
#pragma unroll
        for (int j = 0; j < 2; ++j) {
          const int R = wn * 32 + j * 16 + (lane & 15);
          const s16x8 bfr =
              *(const s16x8*)(smem + 8192 + gI * 8192 + (R * 8 + (ckk ^ (R & 7))) * 16);
#pragma unroll
          for (int i = 0; i < 2; ++i)
            acc[gI][i][j] =
                __builtin_amdgcn_mfma_f32_16x16x32_bf16(af[i], bfr, acc[gI][i][j], 0, 0, 0);
        }
      }
    }
  }

  // epilogue: fast sigmoid (+mem3 fold on rg) -> LDS repack (stride 80) -> 16B stores
  __syncthreads();
  bf16* sm = (bf16*)smem;          // H0 tile [64][80]
  bf16* sr = (bf16*)smem + 5120;   // RG*mem3 tile [64][80]
  const int mb = (lane >> 4) * 4, nb = lane & 15;
#pragma unroll
  for (int i = 0; i < 2; ++i) {
#pragma unroll
    for (int j = 0; j < 2; ++j) {
      const int colL = wn * 32 + j * 16 + nb;
      const int jg = n0 + colL;
      const float c0 = ccat[jg], c1 = ccat[1024 + jg], c2 = ccat[2048 + jg];
      const float m3 = mem_s[jg];
#pragma unroll
      for (int r = 0; r < 4; ++r) {
        const int rowL = wm * 32 + i * 16 + mb + r;
        const float h = fsig(acc[0][i][j][r] + c0) * fsig(acc[1][i][j][r] + c1);
        const float rg = fsig(acc[2][i][j][r] + c2) * m3;
        sm[rowL * 80 + colL] = __float2bfloat16(h);
        sr[rowL * 80 + colL] = __float2bfloat16(rg);
      }
    }
  }
  __syncthreads();
#pragma unroll
  for (int pp = 0; pp < 2; ++pp) {  // 64 rows x 8 chunks = 512 chunks per tile
    const int c = pp * 256 + tid;
    const int row = c >> 3, cc = c & 7;
    const s16x8 v0 = *(const s16x8*)(sm + row * 80 + cc * 8);
    const s16x8 v1 = *(const s16x8*)(sr + row * 80 + cc * 8);
    *(s16x8*)(Hcat + (size_t)(m0 + row) * 2048 + n0 + cc * 8) = v0;
    *(s16x8*)(Hcat + (size_t)(m0 + row) * 2048 + 1024 + n0 + cc * 8) = v1;
  }
}

// ================= out GEMM: 64x64, K=2048, double-buffered, direct store + vout[col] =====
// B = Wcat2 = [WhoB | P]; A = [H0 | rg*mem3]. XCD swizzle keeps per-XCD set in L2.
__global__ __launch_bounds__(256, 4) void gemm_out(const bf16* __restrict__ A,
                                                   const bf16* __restrict__ Bp,
                                                   const float* __restrict__ vout,
                                                   float* __restrict__ outF) {
  __shared__ char smem[32768];  // dbuf: buf0 {A@0,B@8192}, buf1 {A@16384,B@24576}
  const int tid = threadIdx.x, wave = tid >> 6, lane = tid & 63;
  const int wm = wave >> 1, wn = wave & 1;
  const int swz = (blockIdx.x & 7) * 64 + (blockIdx.x >> 3);
  const int m0 = (swz >> 3) * 64, n0 = (swz & 7) * 64;
  f32x4 acc[2][2] = {};

  auto STAGE = [&](int kt, unsigned bofs) {
#pragma unroll
    for (int i = 0; i < 2; ++i) {
      const int ci = i * 256 + tid;
      const int row = ci >> 3, ck = (ci & 7) ^ (row & 7);
      const bf16* g = A + (size_t)(m0 + row) * 2048 + kt + ck * 8;
      const unsigned lofs =
          (unsigned)__builtin_amdgcn_readfirstlane(bofs + (i * 256 + wave * 64) * 16);
      __builtin_amdgcn_global_load_lds(
          (const __attribute__((address_space(1))) void*)g,
          (__attribute__((address_space(3))) void*)(smem + lofs), 16, 0, 0);
    }
#pragma unroll
    for (int i = 0; i < 2; ++i) {
      const int ci = i * 256 + tid;
      const int row = ci >> 3, ck = (ci & 7) ^ (row & 7);
      const bf16* g = Bp + (size_t)(n0 + row) * 2048 + kt + ck * 8;
      const unsigned lofs =
          (unsigned)__builtin_amdgcn_readfirstlane(bofs + 8192 + (i * 256 + wave * 64) * 16);
      __builtin_amdgcn_global_load_lds(
          (const __attribute__((address_space(1))) void*)g,
          (__attribute__((address_space(3))) void*)(smem + lofs), 16, 0, 0);
    }
  };

  STAGE(0, 0);
  __syncthreads();
  unsigned cur = 0;
  for (int kt = 0; kt < 2048; kt += 64) {
    if (kt + 64 < 2048) STAGE(kt + 64, (cur ^ 1u) * 16384u);
#pragma unroll
    for (int ks = 0; ks < 2; ++ks) {
      const int ckk = ks * 4 + (lane >> 4);
      const unsigned cofs = cur * 16384u;
      s16x8 af[2];
#pragma unroll
      for (int i = 0; i < 2; ++i) {
        const int R = wm * 32 + i * 16 + (lane & 15);
        af[i] = *(const s16x8*)(smem + cofs + (R * 8 + (ckk ^ (R & 7))) * 16);
      }
#pragma unroll
      for (int j = 0; j < 2; ++j) {
        const int R = wn * 32 + j * 16 + (lane & 15);
        const s16x8 bfr = *(const s16x8*)(smem + cofs + 8192 + (R * 8 + (ckk ^ (R & 7))) * 16);
#pragma unroll
        for (int i = 0; i < 2; ++i)
          acc[i][j] = __builtin_amdgcn_mfma_f32_16x16x32_bf16(af[i], bfr, acc[i][j], 0, 0, 0);
      }
    }
    __syncthreads();  // drains vmcnt(0)+lgkmcnt(0): next-tile loads landed, all reads done
    cur ^= 1u;
  }

  const int mb = (lane >> 4) * 4, nb = lane & 15;
#pragma unroll
  for (int i = 0; i < 2; ++i) {
#pragma unroll
    for (int j = 0; j < 2; ++j) {
      const int col = n0 + wn * 32 + j * 16 + nb;
#pragma unroll
      for (int r = 0; r < 4; ++r) {
        const int rowg = m0 + wm * 32 + i * 16 + mb + r;
        outF[(size_t)rowg * 512 + col] = acc[i][j][r] + vout[col];
      }
    }
  }
}

extern "C" void kernel_launch(void* const* d_in, const int* in_sizes, int n_in, void* d_out,
                              int out_size, void* d_ws, size_t ws_size, hipStream_t stream) {
  const float* input  = (const float*)d_in[0];
  const float* W_ig   = (const float*)d_in[1];  const float* b_ig   = (const float*)d_in[2];
  const float* W_rig  = (const float*)d_in[3];  const float* b_rig  = (const float*)d_in[4];
  const float* W_mig  = (const float*)d_in[5];  const float* b_mig  = (const float*)d_in[6];
  const float* W_inp  = (const float*)d_in[7];  const float* b_inp  = (const float*)d_in[8];
  const float* W_rinp = (const float*)d_in[9];  const float* b_rinp = (const float*)d_in[10];
  const float* W_rg   = (const float*)d_in[11]; const float* b_rg   = (const float*)d_in[12];
  const float* W_rrg  = (const float*)d_in[13]; const float* b_rrg  = (const float*)d_in[14];
  const float* W_mrg  = (const float*)d_in[15]; const float* b_mrg  = (const float*)d_in[16];
  const float* W_dec  = (const float*)d_in[17]; const float* b_dec  = (const float*)d_in[18];
  const float* W_wg   = (const float*)d_in[19]; const float* b_wg   = (const float*)d_in[20];
  const float* W_rwg  = (const float*)d_in[21]; const float* b_rwg  = (const float*)d_in[22];
  const float* W_mwg  = (const float*)d_in[23]; const float* b_mwg  = (const float*)d_in[24];
  const float* W_enc  = (const float*)d_in[25]; const float* b_enc  = (const float*)d_in[26];
  const float* W_ho   = (const float*)d_in[27];
  (void)W_wg;  // input-side write gate weight: dead (x=0 in steps 0-3; step-4 write gate dead)

  char* ws = (char*)d_ws;
  float* out_s = (float*)(ws + 0);
  float* mem_s = (float*)(ws + 4096);
  float* rgm   = (float*)(ws + 8192);
  float* h0v   = (float*)(ws + 12288);
  float* wgv   = (float*)(ws + 16384);
  float* ccat  = (float*)(ws + 24576);   // 3072 f32
  float* vout  = (float*)(ws + 40960);   // 512 f32
  float* Web   = (float*)(ws + 45056);   // 1024 f32 (Wenc . b_dec)
  bf16* Xb     = (bf16*)(ws + 2162688);                // [4096][512] (4MB)
  bf16* Wcat   = (bf16*)(ws + 6356992);                // [3072][512] (3MB)
  bf16* WhoB   = (bf16*)(ws + 9502720);                // [512][1024] (1MB)
  bf16* Wcat2  = (bf16*)(ws + 10551296);               // [512][2048] = [WhoB | P] (2MB)
  bf16* Wdt    = (bf16*)(ws + 12648448);               // [1024][1024] (2MB)
  bf16* Hcat   = (bf16*)(ws + 14745600);               // [4096][2048] (16MB)
  bf16* Eb     = (bf16*)(ws + 31522816);               // [1024][1024] bf16 (2MB, direct store)
  bf16* WencB  = (bf16*)(ws + 35717120);               // [1024][1024] (2MB)
  bf16* Wg7    = (bf16*)(ws + 37814272);               // [1024][5120] bf16 (10.5MB)

  // setup: casts + transposes + vout/Web + inline step-0 update + Wg7 cast
  setup<<<23552, 256, 0, stream>>>(W_inp, W_ig, W_rg, W_ho, W_dec, W_enc, input,
                                   W_rinp, W_mig, W_rig, W_mrg, W_rrg, W_mwg, W_rwg,
                                   b_inp, b_rinp, b_ig, b_mig, b_rig, b_wg, b_mwg, b_rwg,
                                   b_dec, b_enc, Wcat, WhoB, Wcat2, Wdt, WencB, Xb,
                                   out_s, mem_s, vout, Web, Wg7);

  // steps 1..3: gates (+P/E GEMM riders on first launch) -> fused decode+update
  for (int s = 0; s < 3; ++s) {
    const int pe = (s == 0) ? 384 : 0;
    gates_pe<<<1024 + pe, 256, 0, stream>>>(Wg7, b_inp, b_rinp, b_ig, b_mig, b_rig, b_rg, b_mrg,
                                            b_rrg, b_wg, b_mwg, b_rwg, out_s, mem_s, rgm, h0v,
                                            wgv, WhoB, WencB, Wdt, Wcat2, Eb, pe);
    step_fuse<<<1536, 256, 0, stream>>>(Eb, WencB, Wcat2, WhoB, b_enc, Web, vout, rgm, h0v,
                                        wgv, mem_s, out_s);
  }

  // step-4 constants (ccat) only — M1 scaling folded into gemm_gates epilogue
  final_consts<<<1024, 256, 0, stream>>>(Wg7, b_inp, b_rinp, b_ig, b_mig, b_rig, b_rg, b_mrg,
                                         b_rrg, out_s, mem_s, ccat);

  // gates: Hcat = [sig*sig | sig*mem3] of Xb . [Wi|Wg|Wr]^T + ccat
  gemm_gates<<<1024, 256, 0, stream>>>(Xb, Wcat, ccat, mem_s, Hcat);

  // out = [H0|rg*mem3] . [Who|P]^T + vout  (direct store)
  gemm_out<<<512, 256, 0, stream>>>(Hcat, Wcat2, vout, (float*)d_out);
}

// Round 9
// 214.740 us; speedup vs baseline: 1.0204x; 1.0083x over previous
//
#include <hip/hip_runtime.h>
#include <hip/hip_bf16.h>
#include <math.h>

typedef __hip_bfloat16 bf16;
typedef __attribute__((ext_vector_type(8))) short s16x8;   // 8 bf16 (4 VGPRs)
typedef __attribute__((ext_vector_type(4))) float f32x4;

__device__ __forceinline__ float fsig(float x) {
  return __builtin_amdgcn_rcpf(1.0f + __expf(-x));
}
__device__ __forceinline__ float ftanh(float x) { return 2.0f * fsig(2.0f * x) - 1.0f; }
__device__ __forceinline__ float dot4(float4 a, float4 b) {
  return a.x * b.x + a.y * b.y + a.z * b.z + a.w * b.w;
}
__device__ __forceinline__ float wred(float s) {
#pragma unroll
  for (int off = 32; off > 0; off >>= 1) s += __shfl_down(s, off, 64);
  return s;
}
__device__ __forceinline__ float b2f(unsigned short u) {
  return __uint_as_float((unsigned)u << 16);
}
__device__ __forceinline__ float4 b2f4(ushort4 u) {
  return make_float4(b2f(u.x), b2f(u.y), b2f(u.z), b2f(u.w));
}
__device__ __forceinline__ float dot8(s16x8 v, float4 a, float4 b) {
  return b2f((unsigned short)v[0]) * a.x + b2f((unsigned short)v[1]) * a.y +
         b2f((unsigned short)v[2]) * a.z + b2f((unsigned short)v[3]) * a.w +
         b2f((unsigned short)v[4]) * b.x + b2f((unsigned short)v[5]) * b.y +
         b2f((unsigned short)v[6]) * b.z + b2f((unsigned short)v[7]) * b.w;
}
__device__ __forceinline__ ushort4 f4tob4(float4 v) {
  ushort4 u;
  u.x = __bfloat16_as_ushort(__float2bfloat16(v.x));
  u.y = __bfloat16_as_ushort(__float2bfloat16(v.y));
  u.z = __bfloat16_as_ushort(__float2bfloat16(v.z));
  u.w = __bfloat16_as_ushort(__float2bfloat16(v.w));
  return u;
}

// Wg7 row layout (bf16, 5120 per row): [Wri 0 | Wmig 512 | Wrig 1536 | Wmrg 2048 |
//                                       Wrrg 3072 | Wmwg 3584 | Wrwg 4608]
#define WG7_STRIDE 5120

// ================= setup (bulk Xb/Wcat staging moved to gates_pe riders) =================
// [0,1536):     vectorized casts: Wcat2 left = bf16(W_ho); EW2 left = bf16(W_enc)
// [1536,2560):  Wdt[k][j] = bf16(W_dec[j][k])
// [2560,4096):  merged GEMV: Who rows o<512 -> vout[o]=Who.b_dec, out_s[o]=Who.hidv
//               Wenc rows e=o-512 -> Web[e]=Wenc.b_dec, mem_s[e]=wg*tanh(b_enc+Wenc.hidv)
//               (hidv = step-0 closed form from biases; mem0=0 so no mem read)
// [4096,9216):  cast 7 gate-weight matrices into row-packed bf16 Wg7[1024][5120]
__global__ void setup(const float* __restrict__ W_ho, const float* __restrict__ W_dec,
                      const float* __restrict__ W_enc,
                      const float* __restrict__ Wri, const float* __restrict__ Wmig,
                      const float* __restrict__ Wrig, const float* __restrict__ Wmrg,
                      const float* __restrict__ Wrrg, const float* __restrict__ Wmwg,
                      const float* __restrict__ Wrwg,
                      const float* __restrict__ b_inp, const float* __restrict__ b_rinp,
                      const float* __restrict__ b_ig, const float* __restrict__ b_mig,
                      const float* __restrict__ b_rig, const float* __restrict__ b_wg,
                      const float* __restrict__ b_mwg, const float* __restrict__ b_rwg,
                      const float* __restrict__ b_dec, const float* __restrict__ b_enc,
                      bf16* __restrict__ Wcat2, bf16* __restrict__ Wdt,
                      bf16* __restrict__ EW2,
                      float* __restrict__ out_s, float* __restrict__ mem_s,
                      float* __restrict__ vout, float* __restrict__ Web,
                      bf16* __restrict__ Wg7) {
  __shared__ float t[32][33];
  const int id = blockIdx.x, tid = threadIdx.x;
  if (id < 1536) {
    const int elem = (id * 256 + tid) * 4;  // < 1572864
    if (elem < 524288) {
      const float4 v = *(const float4*)(W_ho + elem);
      *(ushort4*)(Wcat2 + (size_t)(elem >> 10) * 2048 + (elem & 1023)) = f4tob4(v);
    } else {
      const int k = elem - 524288;  // < 1048576
      const float4 v = *(const float4*)(W_enc + k);
      *(ushort4*)(EW2 + (size_t)(k >> 10) * 2048 + (k & 1023)) = f4tob4(v);
    }
  } else if (id < 2560) {
    const int b = id - 1536;
    const int j0 = (b >> 5) * 32, k0 = (b & 31) * 32;
    const int tx = tid & 31, ty = tid >> 5;
#pragma unroll
    for (int r = ty; r < 32; r += 8) t[r][tx] = W_dec[(size_t)(j0 + r) * 1024 + k0 + tx];
    __syncthreads();
#pragma unroll
    for (int r = ty; r < 32; r += 8)
      Wdt[(size_t)(k0 + r) * 1024 + j0 + tx] = __float2bfloat16(t[tx][r]);
  } else if (id < 4096) {
    const int o = id - 2560;  // < 1536
    // hidv[k] inline from biases (exact step-0 closed form)
    const float4 bd = *(const float4*)(b_dec + tid * 4);
    const float4 v1 = *(const float4*)(b_inp + tid * 4);
    const float4 v2 = *(const float4*)(b_rinp + tid * 4);
    const float4 v3 = *(const float4*)(b_ig + tid * 4);
    const float4 v4 = *(const float4*)(b_mig + tid * 4);
    const float4 v5 = *(const float4*)(b_rig + tid * 4);
    float4 hv;
    hv.x = bd.x + fsig(v1.x + v2.x) * fsig(v3.x + v4.x + v5.x);
    hv.y = bd.y + fsig(v1.y + v2.y) * fsig(v3.y + v4.y + v5.y);
    hv.z = bd.z + fsig(v1.z + v2.z) * fsig(v3.z + v4.z + v5.z);
    hv.w = bd.w + fsig(v1.w + v2.w) * fsig(v3.w + v4.w + v5.w);
    const float* row =
        (o < 512) ? (W_ho + (size_t)o * 1024) : (W_enc + (size_t)(o - 512) * 1024);
    const float4 a = *(const float4*)(row + tid * 4);
    const float s1 = wred(dot4(a, bd));   // . b_dec
    const float s2 = wred(dot4(a, hv));   // . hidv
    if ((tid & 63) == 0) {
      t[0][tid >> 6] = s1;
      t[1][tid >> 6] = s2;
    }
    __syncthreads();
    if (tid == 0) {
      const float d1 = t[0][0] + t[0][1] + t[0][2] + t[0][3];
      const float d2 = t[1][0] + t[1][1] + t[1][2] + t[1][3];
      if (o < 512) {
        vout[o] = d1;
        out_s[o] = d2;
      } else {
        const int e = o - 512;
        Web[e] = d1;
        const float wg = fsig(b_wg[e] + b_mwg[e] + b_rwg[e]);
        mem_s[e] = wg * ftanh(b_enc[e] + d2);  // mem0 == 0: no mem_s read
      }
    }
  } else {
    // ---- Wg7 cast: block handles 1024 elems of row j, fifth f ----
    const int b = id - 4096;  // < 5120
    const int j = b / 5, f = b - j * 5;
    const int col = f * 1024 + tid * 4;
    const float* src;
    int c0, stride;
    if (col < 512)       { src = Wri;  c0 = col;        stride = 512; }
    else if (col < 1536) { src = Wmig; c0 = col - 512;  stride = 1024; }
    else if (col < 2048) { src = Wrig; c0 = col - 1536; stride = 512; }
    else if (col < 3072) { src = Wmrg; c0 = col - 2048; stride = 1024; }
    else if (col < 3584) { src = Wrrg; c0 = col - 3072; stride = 512; }
    else if (col < 4608) { src = Wmwg; c0 = col - 3584; stride = 1024; }
    else                 { src = Wrwg; c0 = col - 4608; stride = 512; }
    const float4 v = *(const float4*)(src + (size_t)j * stride + c0);
    *(ushort4*)(Wg7 + (size_t)j * WG7_STRIDE + col) = f4tob4(v);
  }
}

// ================= recurrence stage 1: gates + per-launch rider blocks =================
// riders (blocks [0,riders)):
//   mode 0 (s=0, 384): P = bf16(Wcat2L.Wdt^T) -> Wcat2[:,1024:2048] (128 blocks);
//                      E = bf16(EW2L.Wdt^T)   -> EW2[:,1024:2048]   (256 blocks)
//   mode 1 (s=1, 2048): transpose input [512][4096] f32 -> Xb [4096][512] bf16
//   mode 2 (s=2, 1536): vectorized cast Wcat = bf16([Winp|Wig|Wrg])
// blocks [riders, riders+1024): per-row gates GEMV from bf16 Wg7 (row-packed)
__global__ __launch_bounds__(256) void gates_pe(
    const bf16* __restrict__ Wg7, const float* __restrict__ b_inp,
    const float* __restrict__ b_rinp, const float* __restrict__ b_ig,
    const float* __restrict__ b_mig, const float* __restrict__ b_rig,
    const float* __restrict__ b_rg, const float* __restrict__ b_mrg,
    const float* __restrict__ b_rrg, const float* __restrict__ b_wg,
    const float* __restrict__ b_mwg, const float* __restrict__ b_rwg,
    const float* __restrict__ out_s, const float* __restrict__ mem_s,
    float* __restrict__ rgm, float* __restrict__ h0v, float* __restrict__ wgv,
    const bf16* __restrict__ Wdt, bf16* __restrict__ Wcat2, bf16* __restrict__ EW2,
    const float* __restrict__ input, bf16* __restrict__ Xb,
    const float* __restrict__ W_inp, const float* __restrict__ W_ig,
    const float* __restrict__ W_rg, bf16* __restrict__ Wcat,
    int riders, int mode) {
  __shared__ char smem[32768];  // PE dbuf / transpose tile / GEMV reduction scratch
  const int tid = threadIdx.x;
  if ((int)blockIdx.x >= riders) {
    // ---- gates GEMV path (bf16 weights, one contiguous 10KB row) ----
    float(*red)[4] = (float(*)[4])smem;
    const int j = blockIdx.x - riders, lane = tid & 63, wave = tid >> 6;
    const float4 z = make_float4(0.f, 0.f, 0.f, 0.f);
    const float4 o4 = (tid < 128) ? *(const float4*)(out_s + tid * 4) : z;
    const float4 m4 = *(const float4*)(mem_s + tid * 4);
    const bf16* rowb = Wg7 + (size_t)j * WG7_STRIDE;
    float p[7];
    p[0] = (tid < 128) ? dot4(b2f4(*(const ushort4*)(rowb + tid * 4)), o4) : 0.f;
    p[1] = dot4(b2f4(*(const ushort4*)(rowb + 512 + tid * 4)), m4);
    p[2] = (tid < 128) ? dot4(b2f4(*(const ushort4*)(rowb + 1536 + tid * 4)), o4) : 0.f;
    p[3] = dot4(b2f4(*(const ushort4*)(rowb + 2048 + tid * 4)), m4);
    p[4] = (tid < 128) ? dot4(b2f4(*(const ushort4*)(rowb + 3072 + tid * 4)), o4) : 0.f;
    p[5] = dot4(b2f4(*(const ushort4*)(rowb + 3584 + tid * 4)), m4);
    p[6] = (tid < 128) ? dot4(b2f4(*(const ushort4*)(rowb + 4608 + tid * 4)), o4) : 0.f;
#pragma unroll
    for (int d = 0; d < 7; ++d) {
      float s = wred(p[d]);
      if (lane == 0) red[d][wave] = s;
    }
    __syncthreads();
    if (tid == 0) {
      float D[7];
#pragma unroll
      for (int d = 0; d < 7; ++d) D[d] = red[d][0] + red[d][1] + red[d][2] + red[d][3];
      const float abi = b_inp[j] + b_rinp[j] + D[0];
      const float aig = b_ig[j] + b_mig[j] + b_rig[j] + D[1] + D[2];
      const float arg = b_rg[j] + b_mrg[j] + b_rrg[j] + D[3] + D[4];
      const float awg = b_wg[j] + b_mwg[j] + b_rwg[j] + D[5] + D[6];
      rgm[j] = fsig(arg) * mem_s[j];
      h0v[j] = fsig(abi) * fsig(aig);
      wgv[j] = fsig(awg);
    }
    return;
  }
  if (mode == 1) {
    // ---- Xb transpose rider ----
    float(*t)[33] = (float(*)[33])smem;
    const int b = blockIdx.x;
    const int i0 = (b >> 7) * 32, b0 = (b & 127) * 32;
    const int tx = tid & 31, ty = tid >> 5;
#pragma unroll
    for (int r = ty; r < 32; r += 8) t[r][tx] = input[(size_t)(i0 + r) * 4096 + b0 + tx];
    __syncthreads();
#pragma unroll
    for (int r = ty; r < 32; r += 8)
      Xb[(size_t)(b0 + r) * 512 + i0 + tx] = __float2bfloat16(t[tx][r]);
    return;
  }
  if (mode == 2) {
    // ---- Wcat cast rider (vectorized) ----
    const int elem = ((int)blockIdx.x * 256 + tid) * 4;  // < 1572864
    float4 v;
    if (elem < 524288) v = *(const float4*)(W_inp + elem);
    else if (elem < 1048576) v = *(const float4*)(W_ig + elem - 524288);
    else v = *(const float4*)(W_rg + elem - 1048576);
    *(ushort4*)(Wcat + elem) = f4tob4(v);
    return;
  }
  // ---- mode 0: P/E GEMM rider, double-buffered; A/C in [.|.] 2048-stride buffers ----
  const int bi = blockIdx.x;
  const bf16* Ag;
  bf16* Cg;
  int m0, n0;
  if (bi < 128) {
    Ag = Wcat2; Cg = Wcat2 + 1024;  // P: A = Who rows (left half), C -> right half
    m0 = (bi >> 4) * 64; n0 = (bi & 15) * 64;
  } else {
    const int b2 = bi - 128;  // < 256
    Ag = EW2; Cg = EW2 + 1024;      // E: A = Wenc rows (left half), C -> right half
    m0 = (b2 >> 4) * 64; n0 = (b2 & 15) * 64;
  }
  const int wave = tid >> 6, lane = tid & 63;
  const int wm = wave >> 1, wn = wave & 1;
  f32x4 acc[2][2] = {};

  auto STAGE = [&](int kt, unsigned bofs) {
#pragma unroll
    for (int i = 0; i < 2; ++i) {
      const int ci = i * 256 + tid;
      const int row = ci >> 3, ck = (ci & 7) ^ (row & 7);
      const bf16* g = Ag + (size_t)(m0 + row) * 2048 + kt + ck * 8;
      const unsigned lofs =
          (unsigned)__builtin_amdgcn_readfirstlane(bofs + (i * 256 + wave * 64) * 16);
      __builtin_amdgcn_global_load_lds(
          (const __attribute__((address_space(1))) void*)g,
          (__attribute__((address_space(3))) void*)(smem + lofs), 16, 0, 0);
    }
#pragma unroll
    for (int i = 0; i < 2; ++i) {
      const int ci = i * 256 + tid;
      const int row = ci >> 3, ck = (ci & 7) ^ (row & 7);
      const bf16* g = Wdt + (size_t)(n0 + row) * 1024 + kt + ck * 8;
      const unsigned lofs =
          (unsigned)__builtin_amdgcn_readfirstlane(bofs + 8192 + (i * 256 + wave * 64) * 16);
      __builtin_amdgcn_global_load_lds(
          (const __attribute__((address_space(1))) void*)g,
          (__attribute__((address_space(3))) void*)(smem + lofs), 16, 0, 0);
    }
  };

  STAGE(0, 0);
  __syncthreads();
  unsigned cur = 0;
  for (int kt = 0; kt < 1024; kt += 64) {
    if (kt + 64 < 1024) STAGE(kt + 64, (cur ^ 1u) * 16384u);
#pragma unroll
    for (int ks = 0; ks < 2; ++ks) {
      const int ckk = ks * 4 + (lane >> 4);
      const unsigned cofs = cur * 16384u;
      s16x8 af[2];
#pragma unroll
      for (int i = 0; i < 2; ++i) {
        const int R = wm * 32 + i * 16 + (lane & 15);
        af[i] = *(const s16x8*)(smem + cofs + (R * 8 + (ckk ^ (R & 7))) * 16);
      }
#pragma unroll
      for (int j = 0; j < 2; ++j) {
        const int R = wn * 32 + j * 16 + (lane & 15);
        const s16x8 bfr = *(const s16x8*)(smem + cofs + 8192 + (R * 8 + (ckk ^ (R & 7))) * 16);
#pragma unroll
        for (int i = 0; i < 2; ++i)
          acc[i][j] = __builtin_amdgcn_mfma_f32_16x16x32_bf16(af[i], bfr, acc[i][j], 0, 0, 0);
      }
    }
    __syncthreads();  // drains vmcnt(0)+lgkmcnt(0): next-tile loads landed, all reads done
    cur ^= 1u;
  }
  const int mb = (lane >> 4) * 4, nb = lane & 15;
#pragma unroll
  for (int i = 0; i < 2; ++i) {
#pragma unroll
    for (int j = 0; j < 2; ++j) {
      const int col = n0 + wn * 32 + j * 16 + nb;
#pragma unroll
      for (int r = 0; r < 4; ++r) {
        const int rowg = m0 + wm * 32 + i * 16 + mb + r;
        Cg[(size_t)rowg * 2048 + col] = __float2bfloat16(acc[i][j][r]);
      }
    }
  }
}

// ================= recurrence stage 2: fused decode+update via E/P (unified rows) ========
// hid = b_dec + Wdec.rgm + h0v  (never materialized)
// mem' = (1-wg)mem + wg*tanh(b_enc + Web + Wenc.h0v + E.rgm)   [rows 0..1023, EW2 row]
// out' = vout + Who.h0v + P.rgm                                 [rows 1024..1535, Wcat2 row]
// Each block reads ONE contiguous 4KB bf16 row [left|right]; left cols pair h0v, right rgm.
__global__ void step_fuse(const bf16* __restrict__ EW2, const bf16* __restrict__ Wcat2,
                          const float* __restrict__ b_enc, const float* __restrict__ Web,
                          const float* __restrict__ vout, const float* __restrict__ rgm,
                          const float* __restrict__ h0v, const float* __restrict__ wgv,
                          float* __restrict__ mem_s, float* __restrict__ out_s) {
  __shared__ float red[4];
  const int id = blockIdx.x, tid = threadIdx.x;
  const bf16* row =
      (id < 1024) ? (EW2 + (size_t)id * 2048) : (Wcat2 + (size_t)(id - 1024) * 2048);
  const s16x8 v = *(const s16x8*)(row + tid * 8);
  const int c = (tid * 8) & 1023;
  const float* vec = (tid < 128) ? h0v : rgm;
  const float4 x0 = *(const float4*)(vec + c);
  const float4 x1 = *(const float4*)(vec + c + 4);
  const float s = wred(dot8(v, x0, x1));
  if ((tid & 63) == 0) red[tid >> 6] = s;
  __syncthreads();
  if (tid == 0) {
    const float d = red[0] + red[1] + red[2] + red[3];
    if (id < 1024) {
      const float wg = wgv[id];
      mem_s[id] = (1.0f - wg) * mem_s[id] + wg * ftanh(b_enc[id] + Web[id] + d);
    } else {
      out_s[id - 1024] = vout[id - 1024] + d;
    }
  }
}

// ================= step-4 constants: ccat = [c_bi|c_ig|c_rg] (bf16 Wg7 weights) =========
__global__ void final_consts(const bf16* __restrict__ Wg7, const float* __restrict__ b_inp,
                             const float* __restrict__ b_rinp, const float* __restrict__ b_ig,
                             const float* __restrict__ b_mig, const float* __restrict__ b_rig,
                             const float* __restrict__ b_rg, const float* __restrict__ b_mrg,
                             const float* __restrict__ b_rrg, const float* __restrict__ out_s,
                             const float* __restrict__ mem_s, float* __restrict__ ccat) {
  __shared__ float red[5][4];
  const int id = blockIdx.x, tid = threadIdx.x, lane = tid & 63, wave = tid >> 6;
  const float4 z = make_float4(0.f, 0.f, 0.f, 0.f);
  const float4 o4 = (tid < 128) ? *(const float4*)(out_s + tid * 4) : z;
  const float4 m4 = *(const float4*)(mem_s + tid * 4);
  const bf16* rowb = Wg7 + (size_t)id * WG7_STRIDE;
  float p[5];
  p[0] = (tid < 128) ? dot4(b2f4(*(const ushort4*)(rowb + tid * 4)), o4) : 0.f;
  p[1] = dot4(b2f4(*(const ushort4*)(rowb + 512 + tid * 4)), m4);
  p[2] = (tid < 128) ? dot4(b2f4(*(const ushort4*)(rowb + 1536 + tid * 4)), o4) : 0.f;
  p[3] = dot4(b2f4(*(const ushort4*)(rowb + 2048 + tid * 4)), m4);
  p[4] = (tid < 128) ? dot4(b2f4(*(const ushort4*)(rowb + 3072 + tid * 4)), o4) : 0.f;
#pragma unroll
  for (int d = 0; d < 5; ++d) {
    float s = wred(p[d]);
    if (lane == 0) red[d][wave] = s;
  }
  __syncthreads();
  if (tid == 0) {
    float D[5];
#pragma unroll
    for (int d = 0; d < 5; ++d) D[d] = red[d][0] + red[d][1] + red[d][2] + red[d][3];
    ccat[id] = b_inp[id] + b_rinp[id] + D[0];
    ccat[1024 + id] = b_ig[id] + b_mig[id] + b_rig[id] + D[1] + D[2];
    ccat[2048 + id] = b_rg[id] + b_mrg[id] + b_rrg[id] + D[3] + D[4];
  }
}

// ================= gate GEMM: NG=3, 64x64 tile, fused sigmoid + H0 product =================
// Measured-best form: single-buffered BK=64 @4 blocks/CU (dbuf@2blk -5us R5; BK32 null R7).
// Epilogue folds mem3 into rg (rg*mem3 -> Hcat right). XCD swizzle for L2 locality.
__global__ __launch_bounds__(256, 4) void gemm_gates(const bf16* __restrict__ A,
                                                     const bf16* __restrict__ Wcat,
                                                     const float* __restrict__ ccat,
                                                     const float* __restrict__ mem_s,
                                                     bf16* __restrict__ Hcat) {
  __shared__ char smem[32768];  // A tile 8KB @0; B_g tile 8KB @ 8192+g*8192
  const int tid = threadIdx.x, wave = tid >> 6, lane = tid & 63;
  const int wm = wave >> 1, wn = wave & 1;
  const int swz = (blockIdx.x & 7) * 128 + (blockIdx.x >> 3);
  const int m0 = (swz >> 4) * 64, n0 = (swz & 15) * 64;
  f32x4 acc[3][2][2] = {};

  for (int kt = 0; kt < 512; kt += 64) {
    __syncthreads();
#pragma unroll
    for (int i = 0; i < 2; ++i) {
      const int ci = i * 256 + tid;
      const int row = ci >> 3, ck = (ci & 7) ^ (row & 7);
      const bf16* g = A + (size_t)(m0 + row) * 512 + kt + ck * 8;
      const unsigned lofs = (unsigned)__builtin_amdgcn_readfirstlane((i * 256 + wave * 64) * 16);
      __builtin_amdgcn_global_load_lds(
          (const __attribute__((address_space(1))) void*)g,
          (__attribute__((address_space(3))) void*)(smem + lofs), 16, 0, 0);
    }
#pragma unroll
    for (int gI = 0; gI < 3; ++gI) {
      const bf16* Bp = Wcat + gI * 524288;
#pragma unroll
      for (int i = 0; i < 2; ++i) {
        const int ci = i * 256 + tid;
        const int row = ci >> 3, ck = (ci & 7) ^ (row & 7);
        const bf16* g = Bp + (size_t)(n0 + row) * 512 + kt + ck * 8;
        const unsigned lofs = (unsigned)__builtin_amdgcn_readfirstlane(
            8192 + gI * 8192 + (i * 256 + wave * 64) * 16);
        __builtin_amdgcn_global_load_lds(
            (const __attribute__((address_space(1))) void*)g,
            (__attribute__((address_space(3))) void*)(smem + lofs), 16, 0, 0);
      }
    }
    __syncthreads();

#pragma unroll
    for (int ks = 0; ks < 2; ++ks) {
      const int ckk = ks * 4 + (lane >> 4);
      s16x8 af[2];
#pragma unroll
      for (int i = 0; i < 2; ++i) {
        const int R = wm * 32 + i * 16 + (lane & 15);
        af[i] = *(const s16x8*)(smem + (R * 8 + (ckk ^ (R & 7))) * 16);
      }
#pragma unroll
      for (int gI = 0; gI < 3; ++gI) {
#pragma unroll
        for (int j = 0; j < 2; ++j) {
          const int R = wn * 32 + j * 16 + (lane & 15);
          const s16x8 bfr =
              *(const s16x8*)(smem + 8192 + gI * 8192 + (R * 8 + (ckk ^ (R & 7))) * 16);
#pragma unroll
          for (int i = 0; i < 2; ++i)
            acc[gI][i][j] =
                __builtin_amdgcn_mfma_f32_16x16x32_bf16(af[i], bfr, acc[gI][i][j], 0, 0, 0);
        }
      }
    }
  }

  // epilogue: fast sigmoid (+mem3 fold on rg) -> LDS repack (stride 80) -> 16B stores
  __syncthreads();
  bf16* sm = (bf16*)smem;          // H0 tile [64][80]
  bf16* sr = (bf16*)smem + 5120;   // RG*mem3 tile [64][80]
  const int mb = (lane >> 4) * 4, nb = lane & 15;
#pragma unroll
  for (int i = 0; i < 2; ++i) {
#pragma unroll
    for (int j = 0; j < 2; ++j) {
      const int colL = wn * 32 + j * 16 + nb;
      const int jg = n0 + colL;
      const float c0 = ccat[jg], c1 = ccat[1024 + jg], c2 = ccat[2048 + jg];
      const float m3 = mem_s[jg];
#pragma unroll
      for (int r = 0; r < 4; ++r) {
        const int rowL = wm * 32 + i * 16 + mb + r;
        const float h = fsig(acc[0][i][j][r] + c0) * fsig(acc[1][i][j][r] + c1);
        const float rg = fsig(acc[2][i][j][r] + c2) * m3;
        sm[rowL * 80 + colL] = __float2bfloat16(h);
        sr[rowL * 80 + colL] = __float2bfloat16(rg);
      }
    }
  }
  __syncthreads();
#pragma unroll
  for (int pp = 0; pp < 2; ++pp) {  // 64 rows x 8 chunks = 512 chunks per tile
    const int c = pp * 256 + tid;
    const int row = c >> 3, cc = c & 7;
    const s16x8 v0 = *(const s16x8*)(sm + row * 80 + cc * 8);
    const s16x8 v1 = *(const s16x8*)(sr + row * 80 + cc * 8);
    *(s16x8*)(Hcat + (size_t)(m0 + row) * 2048 + n0 + cc * 8) = v0;
    *(s16x8*)(Hcat + (size_t)(m0 + row) * 2048 + 1024 + n0 + cc * 8) = v1;
  }
}

// ================= out GEMM: 64x64, K=2048, double-buffered, direct store + vout[col] =====
// B = Wcat2 = [WhoB | P]; A = [H0 | rg*mem3]. XCD swizzle keeps per-XCD set in L2.
__global__ __launch_bounds__(256, 4) void gemm_out(const bf16* __restrict__ A,
                                                   const bf16* __restrict__ Bp,
                                                   const float* __restrict__ vout,
                                                   float* __restrict__ outF) {
  __shared__ char smem[32768];  // dbuf: buf0 {A@0,B@8192}, buf1 {A@16384,B@24576}
  const int tid = threadIdx.x, wave = tid >> 6, lane = tid & 63;
  const int wm = wave >> 1, wn = wave & 1;
  const int swz = (blockIdx.x & 7) * 64 + (blockIdx.x >> 3);
  const int m0 = (swz >> 3) * 64, n0 = (swz & 7) * 64;
  f32x4 acc[2][2] = {};

  auto STAGE = [&](int kt, unsigned bofs) {
#pragma unroll
    for (int i = 0; i < 2; ++i) {
      const int ci = i * 256 + tid;
      const int row = ci >> 3, ck = (ci & 7) ^ (row & 7);
      const bf16* g = A + (size_t)(m0 + row) * 2048 + kt + ck * 8;
      const unsigned lofs =
          (unsigned)__builtin_amdgcn_readfirstlane(bofs + (i * 256 + wave * 64) * 16);
      __builtin_amdgcn_global_load_lds(
          (const __attribute__((address_space(1))) void*)g,
          (__attribute__((address_space(3))) void*)(smem + lofs), 16, 0, 0);
    }
#pragma unroll
    for (int i = 0; i < 2; ++i) {
      const int ci = i * 256 + tid;
      const int row = ci >> 3, ck = (ci & 7) ^ (row & 7);
      const bf16* g = Bp + (size_t)(n0 + row) * 2048 + kt + ck * 8;
      const unsigned lofs =
          (unsigned)__builtin_amdgcn_readfirstlane(bofs + 8192 + (i * 256 + wave * 64) * 16);
      __builtin_amdgcn_global_load_lds(
          (const __attribute__((address_space(1))) void*)g,
          (__attribute__((address_space(3))) void*)(smem + lofs), 16, 0, 0);
    }
  };

  STAGE(0, 0);
  __syncthreads();
  unsigned cur = 0;
  for (int kt = 0; kt < 2048; kt += 64) {
    if (kt + 64 < 2048) STAGE(kt + 64, (cur ^ 1u) * 16384u);
#pragma unroll
    for (int ks = 0; ks < 2; ++ks) {
      const int ckk = ks * 4 + (lane >> 4);
      const unsigned cofs = cur * 16384u;
      s16x8 af[2];
#pragma unroll
      for (int i = 0; i < 2; ++i) {
        const int R = wm * 32 + i * 16 + (lane & 15);
        af[i] = *(const s16x8*)(smem + cofs + (R * 8 + (ckk ^ (R & 7))) * 16);
      }
#pragma unroll
      for (int j = 0; j < 2; ++j) {
        const int R = wn * 32 + j * 16 + (lane & 15);
        const s16x8 bfr = *(const s16x8*)(smem + cofs + 8192 + (R * 8 + (ckk ^ (R & 7))) * 16);
#pragma unroll
        for (int i = 0; i < 2; ++i)
          acc[i][j] = __builtin_amdgcn_mfma_f32_16x16x32_bf16(af[i], bfr, acc[i][j], 0, 0, 0);
      }
    }
    __syncthreads();  // drains vmcnt(0)+lgkmcnt(0): next-tile loads landed, all reads done
    cur ^= 1u;
  }

  const int mb = (lane >> 4) * 4, nb = lane & 15;
#pragma unroll
  for (int i = 0; i < 2; ++i) {
#pragma unroll
    for (int j = 0; j < 2; ++j) {
      const int col = n0 + wn * 32 + j * 16 + nb;
#pragma unroll
      for (int r = 0; r < 4; ++r) {
        const int rowg = m0 + wm * 32 + i * 16 + mb + r;
        outF[(size_t)rowg * 512 + col] = acc[i][j][r] + vout[col];
      }
    }
  }
}

extern "C" void kernel_launch(void* const* d_in, const int* in_sizes, int n_in, void* d_out,
                              int out_size, void* d_ws, size_t ws_size, hipStream_t stream) {
  const float* input  = (const float*)d_in[0];
  const float* W_ig   = (const float*)d_in[1];  const float* b_ig   = (const float*)d_in[2];
  const float* W_rig  = (const float*)d_in[3];  const float* b_rig  = (const float*)d_in[4];
  const float* W_mig  = (const float*)d_in[5];  const float* b_mig  = (const float*)d_in[6];
  const float* W_inp  = (const float*)d_in[7];  const float* b_inp  = (const float*)d_in[8];
  const float* W_rinp = (const float*)d_in[9];  const float* b_rinp = (const float*)d_in[10];
  const float* W_rg   = (const float*)d_in[11]; const float* b_rg   = (const float*)d_in[12];
  const float* W_rrg  = (const float*)d_in[13]; const float* b_rrg  = (const float*)d_in[14];
  const float* W_mrg  = (const float*)d_in[15]; const float* b_mrg  = (const float*)d_in[16];
  const float* W_dec  = (const float*)d_in[17]; const float* b_dec  = (const float*)d_in[18];
  const float* W_wg   = (const float*)d_in[19]; const float* b_wg   = (const float*)d_in[20];
  const float* W_rwg  = (const float*)d_in[21]; const float* b_rwg  = (const float*)d_in[22];
  const float* W_mwg  = (const float*)d_in[23]; const float* b_mwg  = (const float*)d_in[24];
  const float* W_enc  = (const float*)d_in[25]; const float* b_enc  = (const float*)d_in[26];
  const float* W_ho   = (const float*)d_in[27];
  (void)W_wg;  // input-side write gate weight: dead (x=0 in steps 0-3; step-4 write gate dead)

  char* ws = (char*)d_ws;
  float* out_s = (float*)(ws + 0);
  float* mem_s = (float*)(ws + 4096);
  float* rgm   = (float*)(ws + 8192);
  float* h0v   = (float*)(ws + 12288);
  float* wgv   = (float*)(ws + 16384);
  float* ccat  = (float*)(ws + 24576);   // 3072 f32
  float* vout  = (float*)(ws + 40960);   // 512 f32
  float* Web   = (float*)(ws + 45056);   // 1024 f32 (Wenc . b_dec)
  bf16* Xb     = (bf16*)(ws + 2162688);                // [4096][512] (4MB)
  bf16* Wcat   = (bf16*)(ws + 6356992);                // [3072][512] (3MB)
  bf16* Wcat2  = (bf16*)(ws + 10551296);               // [512][2048] = [Who | P] (2MB)
  bf16* Wdt    = (bf16*)(ws + 12648448);               // [1024][1024] (2MB)
  bf16* Hcat   = (bf16*)(ws + 14745600);               // [4096][2048] (16MB)
  bf16* EW2    = (bf16*)(ws + 31522816);               // [1024][2048] = [Wenc | E] (4MB)
  bf16* Wg7    = (bf16*)(ws + 37814272);               // [1024][5120] bf16 (10.5MB)

  // setup: Who/Wenc casts + Wdt transpose + merged GEMVs + step-0 update + Wg7 cast
  setup<<<9216, 256, 0, stream>>>(W_ho, W_dec, W_enc,
                                  W_rinp, W_mig, W_rig, W_mrg, W_rrg, W_mwg, W_rwg,
                                  b_inp, b_rinp, b_ig, b_mig, b_rig, b_wg, b_mwg, b_rwg,
                                  b_dec, b_enc, Wcat2, Wdt, EW2, out_s, mem_s, vout, Web, Wg7);

  // steps 1..3: gates + riders {s0: P/E GEMM, s1: Xb transpose, s2: Wcat cast}
  for (int s = 0; s < 3; ++s) {
    const int riders = (s == 0) ? 384 : (s == 1) ? 2048 : 1536;
    const int mode = s;
    gates_pe<<<1024 + riders, 256, 0, stream>>>(
        Wg7, b_inp, b_rinp, b_ig, b_mig, b_rig, b_rg, b_mrg, b_rrg, b_wg, b_mwg, b_rwg,
        out_s, mem_s, rgm, h0v, wgv, Wdt, Wcat2, EW2, input, Xb, W_inp, W_ig, W_rg, Wcat,
        riders, mode);
    step_fuse<<<1536, 256, 0, stream>>>(EW2, Wcat2, b_enc, Web, vout, rgm, h0v, wgv, mem_s,
                                        out_s);
  }

  // step-4 constants (ccat) only — M1 scaling folded into gemm_gates epilogue
  final_consts<<<1024, 256, 0, stream>>>(Wg7, b_inp, b_rinp, b_ig, b_mig, b_rig, b_rg, b_mrg,
                                         b_rrg, out_s, mem_s, ccat);

  // gates: Hcat = [sig*sig | sig*mem3] of Xb . [Wi|Wg|Wr]^T + ccat
  gemm_gates<<<1024, 256, 0, stream>>>(Xb, Wcat, ccat, mem_s, Hcat);

  // out = [H0|rg*mem3] . [Who|P]^T + vout  (direct store)
  gemm_out<<<512, 256, 0, stream>>>(Hcat, Wcat2, vout, (float*)d_out);
}